// Round 3
// baseline (652.192 us; speedup 1.0000x reference)
//
#include <hip/hip_runtime.h>

#define S_TOT 3872
#define C_DIM 1536
#define NHEAD 12
#define DHEAD 128
#define TT 8
#define HH 22
#define WW 22
#define NKT 61          // ceil(3872/64)  key tiles / attn q tiles / ln grid

typedef __bf16 bf16x8 __attribute__((ext_vector_type(8)));
typedef float  f32x4  __attribute__((ext_vector_type(4)));
typedef unsigned short u16x8 __attribute__((ext_vector_type(8)));

__device__ __forceinline__ float bf2f(unsigned short u) {
    unsigned int v = ((unsigned int)u) << 16;
    float f; __builtin_memcpy(&f, &v, 4); return f;
}
__device__ __forceinline__ unsigned short f2bf(float f) {
    unsigned int u; __builtin_memcpy(&u, &f, 4);
    u += 0x7fffu + ((u >> 16) & 1u);
    return (unsigned short)(u >> 16);
}
// truncation-pack two f32 -> bf16x2 dword (internal P only; 1-ulp bias ok)
__device__ __forceinline__ unsigned int pk2_trunc(float a, float b) {
    unsigned int ua, ub;
    __builtin_memcpy(&ua, &a, 4); __builtin_memcpy(&ub, &b, 4);
    return (ua >> 16) | (ub & 0xffff0000u);
}
__device__ __forceinline__ float ldin(const void* p, size_t i, int isf32) {
    if (isf32) return ((const float*)p)[i];
    return bf2f(((const unsigned short*)p)[i]);
}
__device__ __forceinline__ float fexp2(float x) {
#if __has_builtin(__builtin_amdgcn_exp2f)
    return __builtin_amdgcn_exp2f(x);
#else
    return exp2f(x);
#endif
}
__device__ __forceinline__ void async16(const void* g, void* l) {
    __builtin_amdgcn_global_load_lds(
        (const __attribute__((address_space(1))) unsigned int*)g,
        (__attribute__((address_space(3))) unsigned int*)l, 16, 0, 0);
}

// ------- dtype detector + bias/gain conversion (1 block) --------------
__global__ void detect_vecs(const unsigned short* __restrict__ x,
                            const void* p0, const void* p1, const void* p2,
                            const void* p3, const void* p4, const void* p5,
                            int* __restrict__ flag, unsigned short* __restrict__ vecs) {
    __shared__ int cnt;
    if (threadIdx.x == 0) cnt = 0;
    __syncthreads();
    int c = 0;
    for (int i = 0; i < 8; ++i) {
        unsigned short u = x[threadIdx.x * 8 + i];
        int e = (u >> 7) & 0xFF;
        if (e >= 112 && e <= 143) c++;
    }
    atomicAdd(&cnt, c);
    __syncthreads();
    int isf32 = (cnt >= 1900) ? 0 : 1;
    if (threadIdx.x == 0) *flag = isf32;
    const void* ps[6] = {p0, p1, p2, p3, p4, p5};
    for (int v = 0; v < 6; ++v)
        for (int j = threadIdx.x; j < C_DIM; j += 256)
            vecs[v * C_DIM + j] = f2bf(ldin(ps[v], j, isf32));
}

// -------- two weight matrices -> bf16, grid (1152, 2) -----------------
__global__ __launch_bounds__(256) void wconv2(const void* __restrict__ sA,
                                              const void* __restrict__ sB,
                                              const int* __restrict__ flag,
                                              unsigned short* __restrict__ dA,
                                              unsigned short* __restrict__ dB) {
    const void* src = blockIdx.y ? sB : sA;
    unsigned short* dst = blockIdx.y ? dB : dA;
    size_t i = ((size_t)blockIdx.x * 256 + threadIdx.x) * 8;
    if (*flag) {
        const float* s = (const float*)src + i;
        float4 a = *(const float4*)s, b = *(const float4*)(s + 4);
        u16x8 o;
        o[0]=f2bf(a.x); o[1]=f2bf(a.y); o[2]=f2bf(a.z); o[3]=f2bf(a.w);
        o[4]=f2bf(b.x); o[5]=f2bf(b.y); o[6]=f2bf(b.z); o[7]=f2bf(b.w);
        *(u16x8*)(dst + i) = o;
    } else {
        *(u16x8*)(dst + i) = *(const u16x8*)((const unsigned short*)src + i);
    }
}

// ---------------- LayerNorm stats: grid 61, block (64 s x 4 cg) -------
__global__ __launch_bounds__(256) void ln_stats(const void* __restrict__ x,
                                                const int* __restrict__ flag,
                                                float* __restrict__ meanb,
                                                float* __restrict__ rstdb) {
    int isf32 = *flag;
    int sl = threadIdx.x & 63, cg = threadIdx.x >> 6;
    int s = blockIdx.x * 64 + sl;
    float sum = 0.f, sumsq = 0.f;
    if (s < S_TOT) {
        for (int c = cg; c < C_DIM; c += 4) {
            float v = ldin(x, (size_t)c * S_TOT + s, isf32);
            sum += v; sumsq += v * v;
        }
    }
    __shared__ float r0[4][64], r1[4][64];
    r0[cg][sl] = sum; r1[cg][sl] = sumsq;
    __syncthreads();
    if (cg == 0 && s < S_TOT) {
        float st = r0[0][sl] + r0[1][sl] + r0[2][sl] + r0[3][sl];
        float sq = r1[0][sl] + r1[1][sl] + r1[2][sl] + r1[3][sl];
        float m = st * (1.0f / C_DIM);
        float var = sq * (1.0f / C_DIM) - m * m;
        meanb[s] = m;
        rstdb[s] = rsqrtf(var + 1e-6f);
    }
}

// ------------- Normalize + transpose (C,S) -> (S,C) bf16 --------------
__global__ __launch_bounds__(256) void ln_norm_t(const void* __restrict__ x,
                                                 const int* __restrict__ flag,
                                                 const float* __restrict__ meanb,
                                                 const float* __restrict__ rstdb,
                                                 unsigned short* __restrict__ xn) {
    int isf32 = *flag;
    __shared__ float tile[32][33];
    int s0 = blockIdx.x * 32, c0 = blockIdx.y * 32;
    int tx = threadIdx.x, ty = threadIdx.y;   // (32,8)
    for (int r = 0; r < 4; ++r) {
        int cl = ty + 8 * r;
        tile[cl][tx] = ldin(x, (size_t)(c0 + cl) * S_TOT + (s0 + tx), isf32);
    }
    __syncthreads();
    for (int r = 0; r < 4; ++r) {
        int sl = ty + 8 * r;
        int s = s0 + sl, c = c0 + tx;
        xn[(size_t)s * C_DIM + c] = f2bf((tile[tx][sl] - meanb[s]) * rstdb[s]);
    }
}

// ------- MFMA GEMM, m97 replica: 128xBN tile, BK=32, 4 waves 2x2, -----
// 4x(BN/32) frags/wave, linear LDS, gload_lds w16, 2 barriers/K-step.
// Grid 31 x (N/BN) = 744 blocks for N=3072(BN=128) or N=1536(BN=64)
// -> 2.9 blocks/CU, fully co-resident at 3/CU (launch_bounds 256,3).
// D-split: col gn >= nsplit writes D1[gm][gn-nsplit] (fused QK output).
template<int BN, int TRANSV>
__global__ __launch_bounds__(256, 3) void gemm128(const unsigned short* __restrict__ A,
                                                  const unsigned short* __restrict__ W,
                                                  const unsigned short* __restrict__ bias,
                                                  unsigned short* __restrict__ D0,
                                                  unsigned short* __restrict__ D1,
                                                  int nsplit) {
    constexpr int NGRP = 8 + BN / 16;          // 16B-DMA groups per K-step
    constexpr int GPW  = NGRP / 4;             // groups per wave (4 or 3)
    __shared__ __align__(16) unsigned short As[128 * 32];
    __shared__ __align__(16) unsigned short Bs[BN * 32];
    int m0 = blockIdx.x * 128, n0 = blockIdx.y * BN;
    int tid = threadIdx.x;
    int wave = tid >> 6, lane = tid & 63;
    int lm = lane & 15, lq = lane >> 4;
    int wr = wave >> 1, wc = wave & 1;
    int srow = lane >> 2, scol = (lane & 3) * 8;

    f32x4 acc[4][BN / 32];
    #pragma unroll
    for (int a = 0; a < 4; ++a)
        #pragma unroll
        for (int b = 0; b < BN / 32; ++b) acc[a][b] = (f32x4){0.f, 0.f, 0.f, 0.f};

    for (int k0 = 0; k0 < C_DIM; k0 += 32) {
        __syncthreads();
        #pragma unroll
        for (int t = 0; t < GPW; ++t) {
            int g = wave * GPW + t;
            if (g < 8) {
                int am = m0 + g * 16 + srow; if (am > S_TOT - 1) am = S_TOT - 1;
                async16(A + (size_t)am * C_DIM + k0 + scol, (char*)As + g * 1024);
            } else {
                int bn = n0 + (g - 8) * 16 + srow;
                async16(W + (size_t)bn * C_DIM + k0 + scol, (char*)Bs + (g - 8) * 1024);
            }
        }
        __syncthreads();
        bf16x8 af[4], bf[BN / 32];
        #pragma unroll
        for (int mb = 0; mb < 4; ++mb)
            af[mb] = *(const bf16x8*)((const char*)As + (wr * 64 + mb * 16 + lm) * 64 + lq * 16);
        #pragma unroll
        for (int nb = 0; nb < BN / 32; ++nb)
            bf[nb] = *(const bf16x8*)((const char*)Bs + (wc * (BN / 2) + nb * 16 + lm) * 64 + lq * 16);
        #pragma unroll
        for (int mb = 0; mb < 4; ++mb)
            #pragma unroll
            for (int nb = 0; nb < BN / 32; ++nb)
                acc[mb][nb] = __builtin_amdgcn_mfma_f32_16x16x32_bf16(af[mb], bf[nb], acc[mb][nb], 0, 0, 0);
    }

    if (!TRANSV) {
        #pragma unroll
        for (int mb = 0; mb < 4; ++mb)
            #pragma unroll
            for (int nb = 0; nb < BN / 32; ++nb) {
                int gn = n0 + wc * (BN / 2) + nb * 16 + lm;
                unsigned short* dst; int cn;
                if (gn < nsplit) { dst = D0; cn = gn; }
                else             { dst = D1; cn = gn - nsplit; }
                float bv = bf2f(bias[gn]);
                #pragma unroll
                for (int r = 0; r < 4; ++r) {
                    int gm = m0 + wr * 64 + mb * 16 + lq * 4 + r;
                    if (gm < S_TOT) dst[(size_t)gm * C_DIM + cn] = f2bf(acc[mb][nb][r] + bv);
                }
            }
    } else {
        #pragma unroll
        for (int mb = 0; mb < 4; ++mb) {
            int gm0 = m0 + wr * 64 + mb * 16 + lq * 4;
            if (gm0 >= S_TOT) continue;
            #pragma unroll
            for (int nb = 0; nb < BN / 32; ++nb) {
                int gn = n0 + wc * (BN / 2) + nb * 16 + lm;
                float bv = bf2f(bias[gn]);
                ushort4 pk;
                pk.x = f2bf(acc[mb][nb][0] + bv);
                pk.y = f2bf(acc[mb][nb][1] + bv);
                pk.z = f2bf(acc[mb][nb][2] + bv);
                pk.w = f2bf(acc[mb][nb][3] + bv);
                *(ushort4*)(D0 + (size_t)gn * S_TOT + gm0) = pk;
            }
        }
    }
}

// ---------- RMSNorm + RoPE for Q and K in one launch, in-place --------
__global__ __launch_bounds__(256) void rope2(unsigned short* __restrict__ qbuf,
                                             unsigned short* __restrict__ kbuf,
                                             const unsigned short* __restrict__ gq,
                                             const unsigned short* __restrict__ gk,
                                             float qsc) {
    int s = blockIdx.x;
    unsigned short* row = (blockIdx.y ? kbuf : qbuf) + (size_t)s * C_DIM;
    const unsigned short* g = blockIdx.y ? gk : gq;
    float premul = blockIdx.y ? 1.0f : qsc;
    int tid = threadIdx.x;
    float ss = 0.f;
    for (int i = 0; i < 6; ++i) {
        float v = bf2f(row[tid + 256 * i]);
        ss += v * v;
    }
    for (int off = 32; off; off >>= 1) ss += __shfl_down(ss, off, 64);
    __shared__ float wsum[4];
    __shared__ float scale_sh;
    if ((tid & 63) == 0) wsum[tid >> 6] = ss;
    __syncthreads();
    if (tid == 0) {
        float tot = wsum[0] + wsum[1] + wsum[2] + wsum[3];
        scale_sh = rsqrtf(tot * (1.0f / C_DIM) + 1e-6f) * premul;
    }
    __syncthreads();
    float scale = scale_sh;

    int t  = s / (HH * WW);
    int rm = s % (HH * WW);
    int hh = rm / WW, ww = rm % WW;

    float e[3][2];
    int cols[3];
    for (int i = 0; i < 3; ++i) {
        int p = tid + 256 * i;
        int j = p & 63;
        int col0 = (p >> 6) * DHEAD + 2 * j;
        cols[i] = col0;
        float e0 = bf2f(row[col0])     * scale * bf2f(g[col0]);
        float e1 = bf2f(row[col0 + 1]) * scale * bf2f(g[col0 + 1]);
        float pos, fr;
        if (j < 22)       { pos = (float)t;  fr = (float)j        * (1.0f / 22.0f); }
        else if (j < 43)  { pos = (float)hh; fr = (float)(j - 22) * (1.0f / 21.0f); }
        else              { pos = (float)ww; fr = (float)(j - 43) * (1.0f / 21.0f); }
        float ang = pos * expf(fr * -9.210340371976184f);
        float c = cosf(ang), sn = sinf(ang);
        e[i][0] = e0 * c - e1 * sn;
        e[i][1] = e0 * sn + e1 * c;
    }
    for (int i = 0; i < 3; ++i) {
        row[cols[i]]     = f2bf(e[i][0]);
        row[cols[i] + 1] = f2bf(e[i][1]);
    }
}

// ---------------- MFMA flash attention v6 ------------------------------
// v5 minus setprio (m190: setprio hurts barrier-lockstep blocks; our 4
// waves are lockstep). Keeps: gload_lds V staging, xor-swizzled K/V/P
// LDS (bank conflicts 4.97e7 -> 1.42e7 measured), defer-max (T13).
__global__ __launch_bounds__(256) void attn_mfma(const unsigned short* __restrict__ q,
                                                 const unsigned short* __restrict__ kp,
                                                 const unsigned short* __restrict__ vt,
                                                 unsigned short* __restrict__ o) {
    __shared__ __align__(16) unsigned char Ks[16384];  // 16 grp x 4key x 256B (swz)
    __shared__ __align__(16) unsigned char Vs[16384];  // 128 d x 128B keys (swz)
    __shared__ __align__(16) unsigned char Ps[8192];   // 4 waves x 16q x 128B (swz)

    int h  = blockIdx.x / NKT;
    int qt = blockIdx.x % NKT;
    int q0 = qt * 64;
    int tid = threadIdx.x;
    int wave = tid >> 6, lane = tid & 63;
    int lm = lane & 15, lq = lane >> 4;

    // Q as B-operand fragments (lane = q-col, regs = d); pre-scaled by qsc
    bf16x8 qf[4];
    {
        int qr = q0 + wave * 16 + lm; if (qr >= S_TOT) qr = S_TOT - 1;
        const unsigned short* qptr = q + (size_t)qr * C_DIM + h * DHEAD + lq * 8;
        #pragma unroll
        for (int kc = 0; kc < 4; ++kc) qf[kc] = *(const bf16x8*)(qptr + kc * 32);
    }

    // K DMA: group = 4 keys x 128d (1KB); write chunk lane&15, swz by key&7
    int krow = lane >> 4;
    int kcolA = ((lane & 15) ^ krow) * 8;
    int kcolB = ((lane & 15) ^ (4 + krow)) * 8;
    // V DMA: group = 8 d-rows x 64 keys (1KB); key-slot swz by d&7
    int vr8 = lane >> 3;
    int vslot = (lane & 7) ^ vr8;

    int sxor = (lm & 7) << 4;            // read-side xor (key&7 / d&7 / q&7 = lm&7)
    int ksoff[4], kqoff[4];
    #pragma unroll
    for (int nt = 0; nt < 4; ++nt) ksoff[nt] = (nt * 4 + (lm >> 2)) * 1024 + (lm & 3) * 256;
    #pragma unroll
    for (int kc = 0; kc < 4; ++kc) kqoff[kc] = (kc * 4 + lq) * 16;

    f32x4 oacc[8];
    #pragma unroll
    for (int i = 0; i < 8; ++i) oacc[i] = (f32x4){0.f, 0.f, 0.f, 0.f};
    float m_run = -__builtin_inff(), l_run = 0.f;   // scalar: one q per lane

    for (int kt = 0; kt < NKT; ++kt) {
        int k0 = kt * 64;
        __syncthreads();               // prev tile's Ks/Vs/Ps reads complete
        // K tile DMA: 4 groups per wave
        #pragma unroll
        for (int t = 0; t < 4; ++t) {
            int g = wave * 4 + t;
            int grow = k0 + g * 4 + krow; if (grow > S_TOT - 1) grow = S_TOT - 1;
            async16(kp + (size_t)grow * C_DIM + h * DHEAD + ((t & 1) ? kcolB : kcolA),
                    Ks + g * 1024);
        }
        // V tile DMA: 4 groups per wave; clamped lanes only hit invalid keys
        #pragma unroll
        for (int t = 0; t < 4; ++t) {
            int g = wave * 4 + t;
            int vcol = k0 + vslot * 8; if (vcol > S_TOT - 8) vcol = S_TOT - 8;
            async16(vt + (size_t)(h * DHEAD + g * 8 + vr8) * S_TOT + vcol,
                    Vs + g * 1024);
        }
        __syncthreads();               // DMA drained, LDS visible

        // S^T[key][q]: sacc[nt] covers keys nt*16.., cols = q
        f32x4 sacc[4];
        #pragma unroll
        for (int nt = 0; nt < 4; ++nt) sacc[nt] = (f32x4){0.f, 0.f, 0.f, 0.f};
        #pragma unroll
        for (int kc = 0; kc < 4; ++kc)
            #pragma unroll
            for (int nt = 0; nt < 4; ++nt) {
                bf16x8 kf = *(const bf16x8*)(Ks + ((ksoff[nt] + kqoff[kc]) ^ sxor));
                sacc[nt] = __builtin_amdgcn_mfma_f32_16x16x32_bf16(kf, qf[kc], sacc[nt], 0, 0, 0);
            }
        // mask tail keys
        if (kt == NKT - 1) {
            #pragma unroll
            for (int nt = 0; nt < 4; ++nt)
                #pragma unroll
                for (int r = 0; r < 4; ++r)
                    if (k0 + nt * 16 + lq * 4 + r >= S_TOT) sacc[nt][r] = -__builtin_inff();
        }
        // online softmax, base-2, scalar state (q = lm), defer-max (T13)
        float rmax = sacc[0][0];
        #pragma unroll
        for (int nt = 0; nt < 4; ++nt)
            #pragma unroll
            for (int r = 0; r < 4; ++r) rmax = fmaxf(rmax, sacc[nt][r]);
        rmax = fmaxf(rmax, __shfl_xor(rmax, 16, 64));
        rmax = fmaxf(rmax, __shfl_xor(rmax, 32, 64));
        int defer = __all(rmax - m_run <= 8.0f);
        if (!defer) {
            float mn = fmaxf(m_run, rmax);
            float alpha = fexp2(m_run - mn);
            l_run *= alpha;
            #pragma unroll
            for (int i = 0; i < 8; ++i)
                #pragma unroll
                for (int r = 0; r < 4; ++r) oacc[i][r] *= alpha;
            m_run = mn;
        }
        float rs = 0.f;
        #pragma unroll
        for (int nt = 0; nt < 4; ++nt)
            #pragma unroll
            for (int r = 0; r < 4; ++r) {
                float p = fexp2(sacc[nt][r] - m_run);
                sacc[nt][r] = p;
                rs += p;
            }
        rs += __shfl_xor(rs, 16, 64);
        rs += __shfl_xor(rs, 32, 64);
        l_run += rs;
        // P^T -> per-wave LDS (swz): row q=lm, keys nt*16+lq*4..
        #pragma unroll
        for (int nt = 0; nt < 4; ++nt) {
            uint2 pk;
            pk.x = pk2_trunc(sacc[nt][0], sacc[nt][1]);
            pk.y = pk2_trunc(sacc[nt][2], sacc[nt][3]);
            *(uint2*)(Ps + ((wave * 2048 + lm * 128 + nt * 32 + lq * 8) ^ sxor)) = pk;
        }
        // PV: O^T[d][q] += V^T[d][key] * P^T[key][q]
        #pragma unroll
        for (int kc = 0; kc < 2; ++kc) {
            bf16x8 pf = *(const bf16x8*)(Ps + ((wave * 2048 + lm * 128 + kc * 64 + lq * 16) ^ sxor));
            #pragma unroll
            for (int mt = 0; mt < 8; ++mt) {
                bf16x8 vf = *(const bf16x8*)(Vs + ((((mt * 16 + lm) * 128) + kc * 64 + lq * 16) ^ sxor));
                oacc[mt] = __builtin_amdgcn_mfma_f32_16x16x32_bf16(vf, pf, oacc[mt], 0, 0, 0);
            }
        }
    }
    // epilogue: lane owns q-column; d runs over mt/lq/r -> ushort4 stores
    int qrow = q0 + wave * 16 + lm;
    if (qrow < S_TOT) {
        float inv = 1.0f / l_run;
        #pragma unroll
        for (int mt = 0; mt < 8; ++mt) {
            ushort4 pk;
            pk.x = f2bf(oacc[mt][0] * inv);
            pk.y = f2bf(oacc[mt][1] * inv);
            pk.z = f2bf(oacc[mt][2] * inv);
            pk.w = f2bf(oacc[mt][3] * inv);
            *(ushort4*)(o + (size_t)qrow * C_DIM + h * DHEAD + mt * 16 + lq * 4) = pk;
        }
    }
}

// ------ Residual + transpose (S,C) bf16 -> (C,S) out (dual dtype) -----
__global__ __launch_bounds__(256) void resid_t(const unsigned short* __restrict__ proj,
                                               const void* __restrict__ x,
                                               const int* __restrict__ flag,
                                               void* __restrict__ out) {
    int isf32 = *flag;
    __shared__ float tile[32][33];
    int s0 = blockIdx.x * 32, c0 = blockIdx.y * 32;
    int tx = threadIdx.x, ty = threadIdx.y;   // (32,8)
    for (int r = 0; r < 4; ++r) {
        int sl = ty + 8 * r;
        tile[sl][tx] = bf2f(proj[(size_t)(s0 + sl) * C_DIM + (c0 + tx)]);
    }
    __syncthreads();
    for (int r = 0; r < 4; ++r) {
        int cl = ty + 8 * r;
        size_t idx = (size_t)(c0 + cl) * S_TOT + (s0 + tx);
        float val = ldin(x, idx, isf32) + tile[tx][cl];
        if (isf32) ((float*)out)[idx] = val;
        else       ((unsigned short*)out)[idx] = f2bf(val);
    }
}

extern "C" void kernel_launch(void* const* d_in, const int* in_sizes, int n_in,
                              void* d_out, int out_size, void* d_ws, size_t ws_size,
                              hipStream_t stream) {
    const void* x  = d_in[0];
    const void* Wq = d_in[1];
    const void* bq = d_in[2];
    const void* Wk = d_in[3];
    const void* bk = d_in[4];
    const void* Wv = d_in[5];
    const void* bv = d_in[6];
    const void* Wo = d_in[7];
    const void* bo = d_in[8];
    const void* gq = d_in[9];
    const void* gk = d_in[10];

    // ws ~45.2 MB: xn 11.9 | qb 11.9 | kb 11.9 | Wslot0+1 9.4 | small
    char* ws = (char*)d_ws;
    size_t off = 0;
    auto alloc = [&](size_t bytes) -> char* {
        char* p = ws + off;
        off += (bytes + 255) & ~(size_t)255;
        return p;
    };
    const size_t SC = (size_t)S_TOT * C_DIM;
    unsigned short* xn   = (unsigned short*)alloc(SC * 2);
    unsigned short* qb   = (unsigned short*)alloc(SC * 2);
    unsigned short* kb   = (unsigned short*)alloc(SC * 2);
    unsigned short* Ws0  = (unsigned short*)alloc((size_t)C_DIM * C_DIM * 2);
    unsigned short* Ws1  = (unsigned short*)alloc((size_t)C_DIM * C_DIM * 2);
    unsigned short* vecs = (unsigned short*)alloc((size_t)6 * C_DIM * 2);
    float* meanb         = (float*)alloc((size_t)S_TOT * 4);
    float* rstdb         = (float*)alloc((size_t)S_TOT * 4);
    int*   flag          = (int*)alloc(256);
    unsigned short* Vt   = (unsigned short*)d_out;   // [C][S] scratch in d_out
    unsigned short* ob   = xn;   // alias (xn dead after V-GEMM)
    unsigned short* proj = qb;   // alias (qb dead after attn)

    // NOTE: Ws0/Ws1 are contiguous (alloc sizes 256B-aligned), so Ws0 is
    // also the stacked (3072,1536) Wq|Wk matrix, and vecs[0..3071] is the
    // stacked bq|bk bias -> fused QK GEMM.
    unsigned short* bv_b = vecs + 2 * C_DIM;
    unsigned short* bo_b = vecs + 3 * C_DIM;
    unsigned short* gq_b = vecs + 4 * C_DIM;
    unsigned short* gk_b = vecs + 5 * C_DIM;

    const float QSC = 0.12751745f;   // 1/sqrt(128) * log2(e)

    dim3 t328(32, 8);
    dim3 tgrid(S_TOT / 32, C_DIM / 32);             // (121, 48)
    dim3 ggrid(31, 24);                             // 744 blocks, both BN
    dim3 wgrid((C_DIM * C_DIM) / 2048, 2);          // (1152, 2)
    dim3 rgrid(S_TOT, 2);

    detect_vecs<<<1, 256, 0, stream>>>((const unsigned short*)x, bq, bk, bv, bo, gq, gk, flag, vecs);
    wconv2<<<wgrid, 256, 0, stream>>>(Wq, Wk, flag, Ws0, Ws1);
    ln_stats<<<NKT, 256, 0, stream>>>(x, flag, meanb, rstdb);
    ln_norm_t<<<tgrid, t328, 0, stream>>>(x, flag, meanb, rstdb, xn);

    // fused Q+K GEMM: N=3072 (Ws0 = stacked Wq|Wk), split outputs
    gemm128<128, 0><<<ggrid, 256, 0, stream>>>(xn, Ws0, vecs, qb, kb, C_DIM);
    rope2<<<rgrid, 256, 0, stream>>>(qb, kb, gq_b, gk_b, QSC);

    wconv2<<<wgrid, 256, 0, stream>>>(Wv, Wo, flag, Ws0, Ws1);  // slots free again
    gemm128<64, 1><<<ggrid, 256, 0, stream>>>(xn, Ws0, bv_b, Vt, Vt, 1 << 30);

    attn_mfma<<<NHEAD * NKT, 256, 0, stream>>>(qb, kb, Vt, ob);

    gemm128<64, 0><<<ggrid, 256, 0, stream>>>(ob, Ws1, bo_b, proj, proj, 1 << 30);
    resid_t<<<tgrid, t328, 0, stream>>>(proj, x, flag, d_out);
}

// Round 5
// 645.056 us; speedup vs baseline: 1.0111x; 1.0111x over previous
//
#include <hip/hip_runtime.h>

#define S_TOT 3872
#define C_DIM 1536
#define NHEAD 12
#define DHEAD 128
#define TT 8
#define HH 22
#define WW 22
#define NKT 61          // ceil(3872/64)  key tiles / attn q tiles / ln grid

typedef __bf16 bf16x8 __attribute__((ext_vector_type(8)));
typedef float  f32x4  __attribute__((ext_vector_type(4)));
typedef unsigned short u16x8 __attribute__((ext_vector_type(8)));

__device__ __forceinline__ float bf2f(unsigned short u) {
    unsigned int v = ((unsigned int)u) << 16;
    float f; __builtin_memcpy(&f, &v, 4); return f;
}
__device__ __forceinline__ unsigned short f2bf(float f) {
    unsigned int u; __builtin_memcpy(&u, &f, 4);
    u += 0x7fffu + ((u >> 16) & 1u);
    return (unsigned short)(u >> 16);
}
// truncation-pack two f32 -> bf16x2 dword (internal P only; 1-ulp bias ok)
__device__ __forceinline__ unsigned int pk2_trunc(float a, float b) {
    unsigned int ua, ub;
    __builtin_memcpy(&ua, &a, 4); __builtin_memcpy(&ub, &b, 4);
    return (ua >> 16) | (ub & 0xffff0000u);
}
__device__ __forceinline__ float ldin(const void* p, size_t i, int isf32) {
    if (isf32) return ((const float*)p)[i];
    return bf2f(((const unsigned short*)p)[i]);
}
__device__ __forceinline__ float fexp2(float x) {
#if __has_builtin(__builtin_amdgcn_exp2f)
    return __builtin_amdgcn_exp2f(x);
#else
    return exp2f(x);
#endif
}
__device__ __forceinline__ void async16(const void* g, void* l) {
    __builtin_amdgcn_global_load_lds(
        (const __attribute__((address_space(1))) unsigned int*)g,
        (__attribute__((address_space(3))) unsigned int*)l, 16, 0, 0);
}
// bijective XCD-aware block remap (m204): chunk the grid across 8 XCDs
__device__ __forceinline__ int xcd_swz(int bid, int nwg) {
    int q = nwg >> 3, r = nwg & 7;
    int xcd = bid & 7, i = bid >> 3;
    int base = (xcd < r) ? xcd * (q + 1) : r * (q + 1) + (xcd - r) * q;
    return base + i;
}

// ------- dtype detector + bias/gain conversion (1 block) --------------
__global__ void detect_vecs(const unsigned short* __restrict__ x,
                            const void* p0, const void* p1, const void* p2,
                            const void* p3, const void* p4, const void* p5,
                            int* __restrict__ flag, unsigned short* __restrict__ vecs) {
    __shared__ int cnt;
    if (threadIdx.x == 0) cnt = 0;
    __syncthreads();
    int c = 0;
    for (int i = 0; i < 8; ++i) {
        unsigned short u = x[threadIdx.x * 8 + i];
        int e = (u >> 7) & 0xFF;
        if (e >= 112 && e <= 143) c++;
    }
    atomicAdd(&cnt, c);
    __syncthreads();
    int isf32 = (cnt >= 1900) ? 0 : 1;
    if (threadIdx.x == 0) *flag = isf32;
    const void* ps[6] = {p0, p1, p2, p3, p4, p5};
    for (int v = 0; v < 6; ++v)
        for (int j = threadIdx.x; j < C_DIM; j += 256)
            vecs[v * C_DIM + j] = f2bf(ldin(ps[v], j, isf32));
}

// -------- four weight matrices -> bf16, grid (1152, 4) ----------------
__global__ __launch_bounds__(256) void wconv4(const void* __restrict__ s0,
                                              const void* __restrict__ s1,
                                              const void* __restrict__ s2,
                                              const void* __restrict__ s3,
                                              const int* __restrict__ flag,
                                              unsigned short* __restrict__ d0,
                                              unsigned short* __restrict__ d1,
                                              unsigned short* __restrict__ d2,
                                              unsigned short* __restrict__ d3) {
    const void* srcs[4] = {s0, s1, s2, s3};
    unsigned short* dsts[4] = {d0, d1, d2, d3};
    const void* src = srcs[blockIdx.y];
    unsigned short* dst = dsts[blockIdx.y];
    size_t i = ((size_t)blockIdx.x * 256 + threadIdx.x) * 8;
    if (*flag) {
        const float* s = (const float*)src + i;
        float4 a = *(const float4*)s, b = *(const float4*)(s + 4);
        u16x8 o;
        o[0]=f2bf(a.x); o[1]=f2bf(a.y); o[2]=f2bf(a.z); o[3]=f2bf(a.w);
        o[4]=f2bf(b.x); o[5]=f2bf(b.y); o[6]=f2bf(b.z); o[7]=f2bf(b.w);
        *(u16x8*)(dst + i) = o;
    } else {
        *(u16x8*)(dst + i) = *(const u16x8*)((const unsigned short*)src + i);
    }
}

// ---------------- LayerNorm stats: grid 61, block (64 s x 4 cg) -------
__global__ __launch_bounds__(256) void ln_stats(const void* __restrict__ x,
                                                const int* __restrict__ flag,
                                                float* __restrict__ meanb,
                                                float* __restrict__ rstdb) {
    int isf32 = *flag;
    int sl = threadIdx.x & 63, cg = threadIdx.x >> 6;
    int s = blockIdx.x * 64 + sl;
    float sum = 0.f, sumsq = 0.f;
    if (s < S_TOT) {
        for (int c = cg; c < C_DIM; c += 4) {
            float v = ldin(x, (size_t)c * S_TOT + s, isf32);
            sum += v; sumsq += v * v;
        }
    }
    __shared__ float r0[4][64], r1[4][64];
    r0[cg][sl] = sum; r1[cg][sl] = sumsq;
    __syncthreads();
    if (cg == 0 && s < S_TOT) {
        float st = r0[0][sl] + r0[1][sl] + r0[2][sl] + r0[3][sl];
        float sq = r1[0][sl] + r1[1][sl] + r1[2][sl] + r1[3][sl];
        float m = st * (1.0f / C_DIM);
        float var = sq * (1.0f / C_DIM) - m * m;
        meanb[s] = m;
        rstdb[s] = rsqrtf(var + 1e-6f);
    }
}

// ------------- Normalize + transpose (C,S) -> (S,C) bf16 --------------
__global__ __launch_bounds__(256) void ln_norm_t(const void* __restrict__ x,
                                                 const int* __restrict__ flag,
                                                 const float* __restrict__ meanb,
                                                 const float* __restrict__ rstdb,
                                                 unsigned short* __restrict__ xn) {
    int isf32 = *flag;
    __shared__ float tile[32][33];
    int s0 = blockIdx.x * 32, c0 = blockIdx.y * 32;
    int tx = threadIdx.x, ty = threadIdx.y;   // (32,8)
    for (int r = 0; r < 4; ++r) {
        int cl = ty + 8 * r;
        tile[cl][tx] = ldin(x, (size_t)(c0 + cl) * S_TOT + (s0 + tx), isf32);
    }
    __syncthreads();
    for (int r = 0; r < 4; ++r) {
        int sl = ty + 8 * r;
        int s = s0 + sl, c = c0 + tx;
        xn[(size_t)s * C_DIM + c] = f2bf((tile[tx][sl] - meanb[s]) * rstdb[s]);
    }
}

// ------- MFMA GEMM, T3-min 2-phase: 128xBN tile, BK=32, dbuf LDS, -----
// STAGE(t+1) issued BEFORE compute(t), ONE __syncthreads per K-step.
// 4 waves 2x2. Epilogue: gn>=ntrans -> DT transposed; else split at
// nsplit between D0/D1 row-major. XCD-swizzled block ids (T1/m204).
template<int BN>
__global__ __launch_bounds__(256, 3) void gemm2p(const unsigned short* __restrict__ A,
                                                 const unsigned short* __restrict__ W,
                                                 const unsigned short* __restrict__ bias,
                                                 unsigned short* __restrict__ D0,
                                                 unsigned short* __restrict__ D1,
                                                 unsigned short* __restrict__ DT,
                                                 int nsplit, int ntrans) {
    constexpr int NGRP = 8 + BN / 16;          // 1KB DMA groups per K-step
    constexpr int GPW  = NGRP / 4;             // groups per wave
    __shared__ __align__(16) unsigned short As[2][128 * 32];
    __shared__ __align__(16) unsigned short Bs[2][BN * 32];
    int nwg = gridDim.x * gridDim.y;
    int wg  = xcd_swz(blockIdx.y * gridDim.x + blockIdx.x, nwg);
    int m0 = (wg % gridDim.x) * 128, n0 = (wg / gridDim.x) * BN;
    int tid = threadIdx.x;
    int wave = tid >> 6, lane = tid & 63;
    int lm = lane & 15, lq = lane >> 4;
    int wr = wave >> 1, wc = wave & 1;
    int srow = lane >> 2, scol = (lane & 3) * 8;

    f32x4 acc[4][BN / 32];
    #pragma unroll
    for (int a = 0; a < 4; ++a)
        #pragma unroll
        for (int b = 0; b < BN / 32; ++b) acc[a][b] = (f32x4){0.f, 0.f, 0.f, 0.f};

    // prologue: stage k0=0 into buf 0
    #pragma unroll
    for (int t = 0; t < GPW; ++t) {
        int g = wave * GPW + t;
        if (g < 8) {
            int am = m0 + g * 16 + srow; if (am > S_TOT - 1) am = S_TOT - 1;
            async16(A + (size_t)am * C_DIM + scol, (char*)As[0] + g * 1024);
        } else {
            int bn = n0 + (g - 8) * 16 + srow;
            async16(W + (size_t)bn * C_DIM + scol, (char*)Bs[0] + (g - 8) * 1024);
        }
    }
    __syncthreads();
    int cur = 0;
    for (int k0 = 0; k0 < C_DIM; k0 += 32) {
        int kn = k0 + 32;
        if (kn < C_DIM) {
            #pragma unroll
            for (int t = 0; t < GPW; ++t) {
                int g = wave * GPW + t;
                if (g < 8) {
                    int am = m0 + g * 16 + srow; if (am > S_TOT - 1) am = S_TOT - 1;
                    async16(A + (size_t)am * C_DIM + kn + scol, (char*)As[cur ^ 1] + g * 1024);
                } else {
                    int bn = n0 + (g - 8) * 16 + srow;
                    async16(W + (size_t)bn * C_DIM + kn + scol, (char*)Bs[cur ^ 1] + (g - 8) * 1024);
                }
            }
        }
        bf16x8 af[4], bf[BN / 32];
        #pragma unroll
        for (int mb = 0; mb < 4; ++mb)
            af[mb] = *(const bf16x8*)((const char*)As[cur] + (wr * 64 + mb * 16 + lm) * 64 + lq * 16);
        #pragma unroll
        for (int nb = 0; nb < BN / 32; ++nb)
            bf[nb] = *(const bf16x8*)((const char*)Bs[cur] + (wc * (BN / 2) + nb * 16 + lm) * 64 + lq * 16);
        #pragma unroll
        for (int mb = 0; mb < 4; ++mb)
            #pragma unroll
            for (int nb = 0; nb < BN / 32; ++nb)
                acc[mb][nb] = __builtin_amdgcn_mfma_f32_16x16x32_bf16(af[mb], bf[nb], acc[mb][nb], 0, 0, 0);
        __syncthreads();               // drains this step's stage DMAs too
        cur ^= 1;
    }

    #pragma unroll
    for (int mb = 0; mb < 4; ++mb) {
        #pragma unroll
        for (int nb = 0; nb < BN / 32; ++nb) {
            int gn = n0 + wc * (BN / 2) + nb * 16 + lm;
            float bv = bf2f(bias[gn]);
            if (gn >= ntrans) {          // transposed dest (V path)
                int gm0 = m0 + wr * 64 + mb * 16 + lq * 4;
                if (gm0 < S_TOT) {
                    ushort4 pk;
                    pk.x = f2bf(acc[mb][nb][0] + bv);
                    pk.y = f2bf(acc[mb][nb][1] + bv);
                    pk.z = f2bf(acc[mb][nb][2] + bv);
                    pk.w = f2bf(acc[mb][nb][3] + bv);
                    *(ushort4*)(DT + (size_t)(gn - ntrans) * S_TOT + gm0) = pk;
                }
            } else {                     // row-major, split between D0/D1
                unsigned short* dst = (gn < nsplit) ? D0 : D1;
                int cn = (gn < nsplit) ? gn : gn - nsplit;
                #pragma unroll
                for (int r = 0; r < 4; ++r) {
                    int gm = m0 + wr * 64 + mb * 16 + lq * 4 + r;
                    if (gm < S_TOT) dst[(size_t)gm * C_DIM + cn] = f2bf(acc[mb][nb][r] + bv);
                }
            }
        }
    }
}

// ---------- RMSNorm + RoPE for Q and K in one launch, in-place --------
__global__ __launch_bounds__(256) void rope2(unsigned short* __restrict__ qbuf,
                                             unsigned short* __restrict__ kbuf,
                                             const unsigned short* __restrict__ gq,
                                             const unsigned short* __restrict__ gk,
                                             float qsc) {
    int s = blockIdx.x;
    unsigned short* row = (blockIdx.y ? kbuf : qbuf) + (size_t)s * C_DIM;
    const unsigned short* g = blockIdx.y ? gk : gq;
    float premul = blockIdx.y ? 1.0f : qsc;
    int tid = threadIdx.x;
    float ss = 0.f;
    for (int i = 0; i < 6; ++i) {
        float v = bf2f(row[tid + 256 * i]);
        ss += v * v;
    }
    for (int off = 32; off; off >>= 1) ss += __shfl_down(ss, off, 64);
    __shared__ float wsum[4];
    __shared__ float scale_sh;
    if ((tid & 63) == 0) wsum[tid >> 6] = ss;
    __syncthreads();
    if (tid == 0) {
        float tot = wsum[0] + wsum[1] + wsum[2] + wsum[3];
        scale_sh = rsqrtf(tot * (1.0f / C_DIM) + 1e-6f) * premul;
    }
    __syncthreads();
    float scale = scale_sh;

    int t  = s / (HH * WW);
    int rm = s % (HH * WW);
    int hh = rm / WW, ww = rm % WW;

    float e[3][2];
    int cols[3];
    for (int i = 0; i < 3; ++i) {
        int p = tid + 256 * i;
        int j = p & 63;
        int col0 = (p >> 6) * DHEAD + 2 * j;
        cols[i] = col0;
        float e0 = bf2f(row[col0])     * scale * bf2f(g[col0]);
        float e1 = bf2f(row[col0 + 1]) * scale * bf2f(g[col0 + 1]);
        float pos, fr;
        if (j < 22)       { pos = (float)t;  fr = (float)j        * (1.0f / 22.0f); }
        else if (j < 43)  { pos = (float)hh; fr = (float)(j - 22) * (1.0f / 21.0f); }
        else              { pos = (float)ww; fr = (float)(j - 43) * (1.0f / 21.0f); }
        float ang = pos * expf(fr * -9.210340371976184f);
        float c = cosf(ang), sn = sinf(ang);
        e[i][0] = e0 * c - e1 * sn;
        e[i][1] = e0 * sn + e1 * c;
    }
    for (int i = 0; i < 3; ++i) {
        row[cols[i]]     = f2bf(e[i][0]);
        row[cols[i] + 1] = f2bf(e[i][1]);
    }
}

// ---------------- MFMA flash attention v7: T3-min 2-phase -------------
// Double-buffered K/V (72KB LDS -> 2 blocks/CU), STAGE(t+1) before
// compute(t), ONE barrier per tile (61 vs 122). XCD swizzle keeps a
// head's K/V panels (~2MB) resident in one XCD's 4MB L2 -> staging
// latency drops HBM(~900cy) -> L2(~200cy). Keeps R2/R3's verified
// xor-swizzled layouts + defer-max; no setprio (m190).
__global__ __launch_bounds__(256, 2) void attn_mfma(const unsigned short* __restrict__ q,
                                                    const unsigned short* __restrict__ kp,
                                                    const unsigned short* __restrict__ vt,
                                                    unsigned short* __restrict__ o) {
    __shared__ __align__(16) unsigned char Ks[2][16384];  // 16 grp x 4key x 256B (swz)
    __shared__ __align__(16) unsigned char Vs[2][16384];  // 128 d x 128B keys (swz)
    __shared__ __align__(16) unsigned char Ps[8192];      // 4 waves x 16q x 128B (swz)

    int bid = xcd_swz(blockIdx.x, NHEAD * NKT);
    int h  = bid / NKT;
    int qt = bid % NKT;
    int q0 = qt * 64;
    int tid = threadIdx.x;
    int wave = tid >> 6, lane = tid & 63;
    int lm = lane & 15, lq = lane >> 4;

    // Q as B-operand fragments (lane = q-col, regs = d); pre-scaled by qsc
    bf16x8 qf[4];
    {
        int qr = q0 + wave * 16 + lm; if (qr >= S_TOT) qr = S_TOT - 1;
        const unsigned short* qptr = q + (size_t)qr * C_DIM + h * DHEAD + lq * 8;
        #pragma unroll
        for (int kc = 0; kc < 4; ++kc) qf[kc] = *(const bf16x8*)(qptr + kc * 32);
    }

    // K DMA: group = 4 keys x 128d (1KB); write chunk lane&15, swz by key&7
    int krow = lane >> 4;
    int kcolA = ((lane & 15) ^ krow) * 8;
    int kcolB = ((lane & 15) ^ (4 + krow)) * 8;
    // V DMA: group = 8 d-rows x 64 keys (1KB); key-slot swz by d&7
    int vr8 = lane >> 3;
    int vslot = (lane & 7) ^ vr8;

    int sxor = (lm & 7) << 4;            // read-side xor (key&7 / d&7 / q&7 = lm&7)
    int ksoff[4], kqoff[4];
    #pragma unroll
    for (int nt = 0; nt < 4; ++nt) ksoff[nt] = (nt * 4 + (lm >> 2)) * 1024 + (lm & 3) * 256;
    #pragma unroll
    for (int kc = 0; kc < 4; ++kc) kqoff[kc] = (kc * 4 + lq) * 16;

    f32x4 oacc[8];
    #pragma unroll
    for (int i = 0; i < 8; ++i) oacc[i] = (f32x4){0.f, 0.f, 0.f, 0.f};
    float m_run = -__builtin_inff(), l_run = 0.f;   // scalar: one q per lane

#define STAGE_KV(BUF, KT) do {                                              \
        int k0s = (KT) * 64;                                                \
        int vcol = k0s + vslot * 8; if (vcol > S_TOT - 8) vcol = S_TOT - 8; \
        _Pragma("unroll")                                                   \
        for (int t = 0; t < 4; ++t) {                                       \
            int g = wave * 4 + t;                                           \
            int grow = k0s + g * 4 + krow; if (grow > S_TOT - 1) grow = S_TOT - 1; \
            async16(kp + (size_t)grow * C_DIM + h * DHEAD + ((t & 1) ? kcolB : kcolA), \
                    Ks[BUF] + g * 1024);                                    \
            async16(vt + (size_t)(h * DHEAD + g * 8 + vr8) * S_TOT + vcol,  \
                    Vs[BUF] + g * 1024);                                    \
        } } while (0)

    STAGE_KV(0, 0);
    __syncthreads();                   // prologue drain
    int cur = 0;

    for (int kt = 0; kt < NKT; ++kt) {
        int k0 = kt * 64;
        if (kt + 1 < NKT) STAGE_KV(cur ^ 1, kt + 1);   // prefetch next tile
        const unsigned char* Kc = Ks[cur];
        const unsigned char* Vc = Vs[cur];

        // S^T[key][q]: sacc[nt] covers keys nt*16.., cols = q
        f32x4 sacc[4];
        #pragma unroll
        for (int nt = 0; nt < 4; ++nt) sacc[nt] = (f32x4){0.f, 0.f, 0.f, 0.f};
        #pragma unroll
        for (int kc = 0; kc < 4; ++kc)
            #pragma unroll
            for (int nt = 0; nt < 4; ++nt) {
                bf16x8 kf = *(const bf16x8*)(Kc + ((ksoff[nt] + kqoff[kc]) ^ sxor));
                sacc[nt] = __builtin_amdgcn_mfma_f32_16x16x32_bf16(kf, qf[kc], sacc[nt], 0, 0, 0);
            }
        // mask tail keys
        if (kt == NKT - 1) {
            #pragma unroll
            for (int nt = 0; nt < 4; ++nt)
                #pragma unroll
                for (int r = 0; r < 4; ++r)
                    if (k0 + nt * 16 + lq * 4 + r >= S_TOT) sacc[nt][r] = -__builtin_inff();
        }
        // online softmax, base-2, scalar state (q = lm), defer-max (T13)
        float rmax = sacc[0][0];
        #pragma unroll
        for (int nt = 0; nt < 4; ++nt)
            #pragma unroll
            for (int r = 0; r < 4; ++r) rmax = fmaxf(rmax, sacc[nt][r]);
        rmax = fmaxf(rmax, __shfl_xor(rmax, 16, 64));
        rmax = fmaxf(rmax, __shfl_xor(rmax, 32, 64));
        int defer = __all(rmax - m_run <= 8.0f);
        if (!defer) {
            float mn = fmaxf(m_run, rmax);
            float alpha = fexp2(m_run - mn);
            l_run *= alpha;
            #pragma unroll
            for (int i = 0; i < 8; ++i)
                #pragma unroll
                for (int r = 0; r < 4; ++r) oacc[i][r] *= alpha;
            m_run = mn;
        }
        float rs = 0.f;
        #pragma unroll
        for (int nt = 0; nt < 4; ++nt)
            #pragma unroll
            for (int r = 0; r < 4; ++r) {
                float p = fexp2(sacc[nt][r] - m_run);
                sacc[nt][r] = p;
                rs += p;
            }
        rs += __shfl_xor(rs, 16, 64);
        rs += __shfl_xor(rs, 32, 64);
        l_run += rs;
        // P^T -> per-wave LDS (swz): row q=lm, keys nt*16+lq*4..
        #pragma unroll
        for (int nt = 0; nt < 4; ++nt) {
            uint2 pk;
            pk.x = pk2_trunc(sacc[nt][0], sacc[nt][1]);
            pk.y = pk2_trunc(sacc[nt][2], sacc[nt][3]);
            *(uint2*)(Ps + ((wave * 2048 + lm * 128 + nt * 32 + lq * 8) ^ sxor)) = pk;
        }
        // PV: O^T[d][q] += V^T[d][key] * P^T[key][q]
        #pragma unroll
        for (int kc = 0; kc < 2; ++kc) {
            bf16x8 pf = *(const bf16x8*)(Ps + ((wave * 2048 + lm * 128 + kc * 64 + lq * 16) ^ sxor));
            #pragma unroll
            for (int mt = 0; mt < 8; ++mt) {
                bf16x8 vf = *(const bf16x8*)(Vc + ((((mt * 16 + lm) * 128) + kc * 64 + lq * 16) ^ sxor));
                oacc[mt] = __builtin_amdgcn_mfma_f32_16x16x32_bf16(vf, pf, oacc[mt], 0, 0, 0);
            }
        }
        __syncthreads();               // next tile staged + this tile's reads done
        cur ^= 1;
    }
#undef STAGE_KV
    // epilogue: lane owns q-column; d runs over mt/lq/r -> ushort4 stores
    int qrow = q0 + wave * 16 + lm;
    if (qrow < S_TOT) {
        float inv = 1.0f / l_run;
        #pragma unroll
        for (int mt = 0; mt < 8; ++mt) {
            ushort4 pk;
            pk.x = f2bf(oacc[mt][0] * inv);
            pk.y = f2bf(oacc[mt][1] * inv);
            pk.z = f2bf(oacc[mt][2] * inv);
            pk.w = f2bf(oacc[mt][3] * inv);
            *(ushort4*)(o + (size_t)qrow * C_DIM + h * DHEAD + mt * 16 + lq * 4) = pk;
        }
    }
}

// ------ Residual + transpose (S,C) bf16 -> (C,S) out (dual dtype) -----
__global__ __launch_bounds__(256) void resid_t(const unsigned short* __restrict__ proj,
                                               const void* __restrict__ x,
                                               const int* __restrict__ flag,
                                               void* __restrict__ out) {
    int isf32 = *flag;
    __shared__ float tile[32][33];
    int s0 = blockIdx.x * 32, c0 = blockIdx.y * 32;
    int tx = threadIdx.x, ty = threadIdx.y;   // (32,8)
    for (int r = 0; r < 4; ++r) {
        int sl = ty + 8 * r;
        tile[sl][tx] = bf2f(proj[(size_t)(s0 + sl) * C_DIM + (c0 + tx)]);
    }
    __syncthreads();
    for (int r = 0; r < 4; ++r) {
        int cl = ty + 8 * r;
        size_t idx = (size_t)(c0 + cl) * S_TOT + (s0 + tx);
        float val = ldin(x, idx, isf32) + tile[tx][cl];
        if (isf32) ((float*)out)[idx] = val;
        else       ((unsigned short*)out)[idx] = f2bf(val);
    }
}

extern "C" void kernel_launch(void* const* d_in, const int* in_sizes, int n_in,
                              void* d_out, int out_size, void* d_ws, size_t ws_size,
                              hipStream_t stream) {
    const void* x  = d_in[0];
    const void* Wq = d_in[1];
    const void* bq = d_in[2];
    const void* Wk = d_in[3];
    const void* bk = d_in[4];
    const void* Wv = d_in[5];
    const void* bv = d_in[6];
    const void* Wo = d_in[7];
    const void* bo = d_in[8];
    const void* gq = d_in[9];
    const void* gk = d_in[10];

    // ws ~55 MB: xn 11.9 | qb 11.9 | kb 11.9 | Ws0..3 18.9 | small
    char* ws = (char*)d_ws;
    size_t off = 0;
    auto alloc = [&](size_t bytes) -> char* {
        char* p = ws + off;
        off += (bytes + 255) & ~(size_t)255;
        return p;
    };
    const size_t SC = (size_t)S_TOT * C_DIM;
    const size_t WSZ = (size_t)C_DIM * C_DIM * 2;   // 4718592, 256B-aligned
    unsigned short* xn   = (unsigned short*)alloc(SC * 2);
    unsigned short* qb   = (unsigned short*)alloc(SC * 2);
    unsigned short* kb   = (unsigned short*)alloc(SC * 2);
    unsigned short* Ws0  = (unsigned short*)alloc(WSZ);  // Wq (stack head)
    unsigned short* Ws1  = (unsigned short*)alloc(WSZ);  // Wk (contiguous)
    unsigned short* Ws2  = (unsigned short*)alloc(WSZ);  // Wv (contiguous)
    unsigned short* Ws3  = (unsigned short*)alloc(WSZ);  // Wo
    unsigned short* vecs = (unsigned short*)alloc((size_t)6 * C_DIM * 2);
    float* meanb         = (float*)alloc((size_t)S_TOT * 4);
    float* rstdb         = (float*)alloc((size_t)S_TOT * 4);
    int*   flag          = (int*)alloc(256);
    unsigned short* Vt   = (unsigned short*)d_out;   // [C][S] scratch in d_out
    unsigned short* ob   = xn;   // alias (xn dead after QKV-GEMM)
    unsigned short* proj = qb;   // alias (qb dead after attn)

    (void)Ws1; (void)Ws2;   // accessed via the Ws0 stacked view in gemm2p

    // vecs layout: bq|bk|bv|bo|gq|gk  -> vecs[0..4607] = stacked QKV bias
    unsigned short* bo_b = vecs + 3 * C_DIM;
    unsigned short* gq_b = vecs + 4 * C_DIM;
    unsigned short* gk_b = vecs + 5 * C_DIM;

    const float QSC = 0.12751745f;   // 1/sqrt(128) * log2(e)

    dim3 t328(32, 8);
    dim3 tgrid(S_TOT / 32, C_DIM / 32);             // (121, 48)
    dim3 qkvgrid(31, 36);                           // 1116 blocks, N=4608
    dim3 ogrid(31, 24);                             // 744 blocks, N=1536
    dim3 wgrid((C_DIM * C_DIM) / 2048, 4);          // (1152, 4)
    dim3 rgrid(S_TOT, 2);

    detect_vecs<<<1, 256, 0, stream>>>((const unsigned short*)x, bq, bk, bv, bo, gq, gk, flag, vecs);
    wconv4<<<wgrid, 256, 0, stream>>>(Wq, Wk, Wv, Wo, flag, Ws0, Ws1, Ws2, Ws3);
    ln_stats<<<NKT, 256, 0, stream>>>(x, flag, meanb, rstdb);
    ln_norm_t<<<tgrid, t328, 0, stream>>>(x, flag, meanb, rstdb, xn);

    // fused QKV GEMM: N=4608 (Ws0 = stacked Wq|Wk|Wv), Q->qb, K->kb,
    // V->Vt (transposed [C][S])
    gemm2p<128><<<qkvgrid, 256, 0, stream>>>(xn, Ws0, vecs, qb, kb, Vt, C_DIM, 2 * C_DIM);
    rope2<<<rgrid, 256, 0, stream>>>(qb, kb, gq_b, gk_b, QSC);

    attn_mfma<<<NHEAD * NKT, 256, 0, stream>>>(qb, kb, Vt, ob);

    gemm2p<64><<<ogrid, 256, 0, stream>>>(ob, Ws3, bo_b, proj, proj, proj, 1 << 30, 1 << 30);
    resid_t<<<tgrid, t328, 0, stream>>>(proj, x, flag, d_out);
}

// Round 7
// 632.587 us; speedup vs baseline: 1.0310x; 1.0197x over previous
//
#include <hip/hip_runtime.h>

#define S_TOT 3872
#define C_DIM 1536
#define NHEAD 12
#define DHEAD 128
#define TT 8
#define HH 22
#define WW 22
#define NKT 61          // ceil(3872/64)  key tiles / attn q tiles / ln grid

typedef __bf16 bf16x8 __attribute__((ext_vector_type(8)));
typedef float  f32x4  __attribute__((ext_vector_type(4)));
typedef unsigned short u16x8 __attribute__((ext_vector_type(8)));

__device__ __forceinline__ float bf2f(unsigned short u) {
    unsigned int v = ((unsigned int)u) << 16;
    float f; __builtin_memcpy(&f, &v, 4); return f;
}
__device__ __forceinline__ unsigned short f2bf(float f) {
    unsigned int u; __builtin_memcpy(&u, &f, 4);
    u += 0x7fffu + ((u >> 16) & 1u);
    return (unsigned short)(u >> 16);
}
// truncation-pack two f32 -> bf16x2 dword (internal P only; 1-ulp bias ok)
__device__ __forceinline__ unsigned int pk2_trunc(float a, float b) {
    unsigned int ua, ub;
    __builtin_memcpy(&ua, &a, 4); __builtin_memcpy(&ub, &b, 4);
    return (ua >> 16) | (ub & 0xffff0000u);
}
__device__ __forceinline__ float ldin(const void* p, size_t i, int isf32) {
    if (isf32) return ((const float*)p)[i];
    return bf2f(((const unsigned short*)p)[i]);
}
__device__ __forceinline__ float fexp2(float x) {
#if __has_builtin(__builtin_amdgcn_exp2f)
    return __builtin_amdgcn_exp2f(x);
#else
    return exp2f(x);
#endif
}
__device__ __forceinline__ void async16(const void* g, void* l) {
    __builtin_amdgcn_global_load_lds(
        (const __attribute__((address_space(1))) unsigned int*)g,
        (__attribute__((address_space(3))) unsigned int*)l, 16, 0, 0);
}
// bijective XCD-aware block remap (m204): chunk the grid across 8 XCDs
__device__ __forceinline__ int xcd_swz(int bid, int nwg) {
    int q = nwg >> 3, r = nwg & 7;
    int xcd = bid & 7, i = bid >> 3;
    int base = (xcd < r) ? xcd * (q + 1) : r * (q + 1) + (xcd - r) * q;
    return base + i;
}

// ------- dtype detector + bias/gain conversion (1 block) --------------
__global__ void detect_vecs(const unsigned short* __restrict__ x,
                            const void* p0, const void* p1, const void* p2,
                            const void* p3, const void* p4, const void* p5,
                            int* __restrict__ flag, unsigned short* __restrict__ vecs) {
    __shared__ int cnt;
    if (threadIdx.x == 0) cnt = 0;
    __syncthreads();
    int c = 0;
    for (int i = 0; i < 8; ++i) {
        unsigned short u = x[threadIdx.x * 8 + i];
        int e = (u >> 7) & 0xFF;
        if (e >= 112 && e <= 143) c++;
    }
    atomicAdd(&cnt, c);
    __syncthreads();
    int isf32 = (cnt >= 1900) ? 0 : 1;
    if (threadIdx.x == 0) *flag = isf32;
    const void* ps[6] = {p0, p1, p2, p3, p4, p5};
    for (int v = 0; v < 6; ++v)
        for (int j = threadIdx.x; j < C_DIM; j += 256)
            vecs[v * C_DIM + j] = f2bf(ldin(ps[v], j, isf32));
}

// -------- four weight matrices -> bf16, grid (1152, 4) ----------------
__global__ __launch_bounds__(256) void wconv4(const void* __restrict__ s0,
                                              const void* __restrict__ s1,
                                              const void* __restrict__ s2,
                                              const void* __restrict__ s3,
                                              const int* __restrict__ flag,
                                              unsigned short* __restrict__ d0,
                                              unsigned short* __restrict__ d1,
                                              unsigned short* __restrict__ d2,
                                              unsigned short* __restrict__ d3) {
    const void* srcs[4] = {s0, s1, s2, s3};
    unsigned short* dsts[4] = {d0, d1, d2, d3};
    const void* src = srcs[blockIdx.y];
    unsigned short* dst = dsts[blockIdx.y];
    size_t i = ((size_t)blockIdx.x * 256 + threadIdx.x) * 8;
    if (*flag) {
        const float* s = (const float*)src + i;
        float4 a = *(const float4*)s, b = *(const float4*)(s + 4);
        u16x8 o;
        o[0]=f2bf(a.x); o[1]=f2bf(a.y); o[2]=f2bf(a.z); o[3]=f2bf(a.w);
        o[4]=f2bf(b.x); o[5]=f2bf(b.y); o[6]=f2bf(b.z); o[7]=f2bf(b.w);
        *(u16x8*)(dst + i) = o;
    } else {
        *(u16x8*)(dst + i) = *(const u16x8*)((const unsigned short*)src + i);
    }
}

// ---------------- LayerNorm stats: grid 61, block (64 s x 4 cg) -------
__global__ __launch_bounds__(256) void ln_stats(const void* __restrict__ x,
                                                const int* __restrict__ flag,
                                                float* __restrict__ meanb,
                                                float* __restrict__ rstdb) {
    int isf32 = *flag;
    int sl = threadIdx.x & 63, cg = threadIdx.x >> 6;
    int s = blockIdx.x * 64 + sl;
    float sum = 0.f, sumsq = 0.f;
    if (s < S_TOT) {
        for (int c = cg; c < C_DIM; c += 4) {
            float v = ldin(x, (size_t)c * S_TOT + s, isf32);
            sum += v; sumsq += v * v;
        }
    }
    __shared__ float r0[4][64], r1[4][64];
    r0[cg][sl] = sum; r1[cg][sl] = sumsq;
    __syncthreads();
    if (cg == 0 && s < S_TOT) {
        float st = r0[0][sl] + r0[1][sl] + r0[2][sl] + r0[3][sl];
        float sq = r1[0][sl] + r1[1][sl] + r1[2][sl] + r1[3][sl];
        float m = st * (1.0f / C_DIM);
        float var = sq * (1.0f / C_DIM) - m * m;
        meanb[s] = m;
        rstdb[s] = rsqrtf(var + 1e-6f);
    }
}

// ------------- Normalize + transpose (C,S) -> (S,C) bf16 --------------
__global__ __launch_bounds__(256) void ln_norm_t(const void* __restrict__ x,
                                                 const int* __restrict__ flag,
                                                 const float* __restrict__ meanb,
                                                 const float* __restrict__ rstdb,
                                                 unsigned short* __restrict__ xn) {
    int isf32 = *flag;
    __shared__ float tile[32][33];
    int s0 = blockIdx.x * 32, c0 = blockIdx.y * 32;
    int tx = threadIdx.x, ty = threadIdx.y;   // (32,8)
    for (int r = 0; r < 4; ++r) {
        int cl = ty + 8 * r;
        tile[cl][tx] = ldin(x, (size_t)(c0 + cl) * S_TOT + (s0 + tx), isf32);
    }
    __syncthreads();
    for (int r = 0; r < 4; ++r) {
        int sl = ty + 8 * r;
        int s = s0 + sl, c = c0 + tx;
        xn[(size_t)s * C_DIM + c] = f2bf((tile[tx][sl] - meanb[s]) * rstdb[s]);
    }
}

// ------- MFMA GEMM, T3+T4: 128xBN tile, BK=32, dbuf LDS, COUNTED ------
// vmcnt + RAW barriers (m218 pattern). Per K-step: STAGE(t+1) issued,
// then vmcnt(GPW) waits only the PREVIOUS stage (new one stays in
// flight across the barrier), raw s_barrier, ds_read+MFMA, raw
// s_barrier (reads done -> buffer overwritable next iter).
template<int BN>
__global__ __launch_bounds__(256, 3) void gemm2p(const unsigned short* __restrict__ A,
                                                 const unsigned short* __restrict__ W,
                                                 const unsigned short* __restrict__ bias,
                                                 unsigned short* __restrict__ D0,
                                                 unsigned short* __restrict__ D1,
                                                 unsigned short* __restrict__ DT,
                                                 int nsplit, int ntrans) {
    constexpr int NGRP = 8 + BN / 16;          // 1KB DMA groups per K-step
    constexpr int GPW  = NGRP / 4;             // groups per wave = loads/thread
    __shared__ __align__(16) unsigned short As[2][128 * 32];
    __shared__ __align__(16) unsigned short Bs[2][BN * 32];
    int nwg = gridDim.x * gridDim.y;
    int wg  = xcd_swz(blockIdx.y * gridDim.x + blockIdx.x, nwg);
    int m0 = (wg % gridDim.x) * 128, n0 = (wg / gridDim.x) * BN;
    int tid = threadIdx.x;
    int wave = tid >> 6, lane = tid & 63;
    int lm = lane & 15, lq = lane >> 4;
    int wr = wave >> 1, wc = wave & 1;
    int srow = lane >> 2, scol = (lane & 3) * 8;

    f32x4 acc[4][BN / 32];
    #pragma unroll
    for (int a = 0; a < 4; ++a)
        #pragma unroll
        for (int b = 0; b < BN / 32; ++b) acc[a][b] = (f32x4){0.f, 0.f, 0.f, 0.f};

    // prologue: stage k0=0 into buf 0 (stays in flight until loop's vmcnt)
    #pragma unroll
    for (int t = 0; t < GPW; ++t) {
        int g = wave * GPW + t;
        if (g < 8) {
            int am = m0 + g * 16 + srow; if (am > S_TOT - 1) am = S_TOT - 1;
            async16(A + (size_t)am * C_DIM + scol, (char*)As[0] + g * 1024);
        } else {
            int bn = n0 + (g - 8) * 16 + srow;
            async16(W + (size_t)bn * C_DIM + scol, (char*)Bs[0] + (g - 8) * 1024);
        }
    }
    int cur = 0;
    for (int k0 = 0; k0 < C_DIM; k0 += 32) {
        int kn = k0 + 32;
        if (kn < C_DIM) {
            #pragma unroll
            for (int t = 0; t < GPW; ++t) {
                int g = wave * GPW + t;
                if (g < 8) {
                    int am = m0 + g * 16 + srow; if (am > S_TOT - 1) am = S_TOT - 1;
                    async16(A + (size_t)am * C_DIM + kn + scol, (char*)As[cur ^ 1] + g * 1024);
                } else {
                    int bn = n0 + (g - 8) * 16 + srow;
                    async16(W + (size_t)bn * C_DIM + kn + scol, (char*)Bs[cur ^ 1] + (g - 8) * 1024);
                }
            }
            // wait only the PREVIOUS stage (GPW newest stay in flight)
            asm volatile("s_waitcnt vmcnt(%0)" :: "i"(GPW) : "memory");
        } else {
            asm volatile("s_waitcnt vmcnt(0)" ::: "memory");
        }
        __builtin_amdgcn_sched_barrier(0);
        __builtin_amdgcn_s_barrier();          // all waves' prev stage landed
        __builtin_amdgcn_sched_barrier(0);

        bf16x8 af[4], bf[BN / 32];
        #pragma unroll
        for (int mb = 0; mb < 4; ++mb)
            af[mb] = *(const bf16x8*)((const char*)As[cur] + (wr * 64 + mb * 16 + lm) * 64 + lq * 16);
        #pragma unroll
        for (int nb = 0; nb < BN / 32; ++nb)
            bf[nb] = *(const bf16x8*)((const char*)Bs[cur] + (wc * (BN / 2) + nb * 16 + lm) * 64 + lq * 16);
        #pragma unroll
        for (int mb = 0; mb < 4; ++mb)
            #pragma unroll
            for (int nb = 0; nb < BN / 32; ++nb)
                acc[mb][nb] = __builtin_amdgcn_mfma_f32_16x16x32_bf16(af[mb], bf[nb], acc[mb][nb], 0, 0, 0);

        __builtin_amdgcn_sched_barrier(0);
        __builtin_amdgcn_s_barrier();          // reads done; buf free to overwrite
        __builtin_amdgcn_sched_barrier(0);
        cur ^= 1;
    }

    #pragma unroll
    for (int mb = 0; mb < 4; ++mb) {
        #pragma unroll
        for (int nb = 0; nb < BN / 32; ++nb) {
            int gn = n0 + wc * (BN / 2) + nb * 16 + lm;
            float bv = bf2f(bias[gn]);
            if (gn >= ntrans) {          // transposed dest (V path)
                int gm0 = m0 + wr * 64 + mb * 16 + lq * 4;
                if (gm0 < S_TOT) {
                    ushort4 pk;
                    pk.x = f2bf(acc[mb][nb][0] + bv);
                    pk.y = f2bf(acc[mb][nb][1] + bv);
                    pk.z = f2bf(acc[mb][nb][2] + bv);
                    pk.w = f2bf(acc[mb][nb][3] + bv);
                    *(ushort4*)(DT + (size_t)(gn - ntrans) * S_TOT + gm0) = pk;
                }
            } else {                     // row-major, split between D0/D1
                unsigned short* dst = (gn < nsplit) ? D0 : D1;
                int cn = (gn < nsplit) ? gn : gn - nsplit;
                #pragma unroll
                for (int r = 0; r < 4; ++r) {
                    int gm = m0 + wr * 64 + mb * 16 + lq * 4 + r;
                    if (gm < S_TOT) dst[(size_t)gm * C_DIM + cn] = f2bf(acc[mb][nb][r] + bv);
                }
            }
        }
    }
}

// ---------- RMSNorm + RoPE for Q and K in one launch, in-place --------
__global__ __launch_bounds__(256) void rope2(unsigned short* __restrict__ qbuf,
                                             unsigned short* __restrict__ kbuf,
                                             const unsigned short* __restrict__ gq,
                                             const unsigned short* __restrict__ gk,
                                             float qsc) {
    int s = blockIdx.x;
    unsigned short* row = (blockIdx.y ? kbuf : qbuf) + (size_t)s * C_DIM;
    const unsigned short* g = blockIdx.y ? gk : gq;
    float premul = blockIdx.y ? 1.0f : qsc;
    int tid = threadIdx.x;
    float ss = 0.f;
    for (int i = 0; i < 6; ++i) {
        float v = bf2f(row[tid + 256 * i]);
        ss += v * v;
    }
    for (int off = 32; off; off >>= 1) ss += __shfl_down(ss, off, 64);
    __shared__ float wsum[4];
    __shared__ float scale_sh;
    if ((tid & 63) == 0) wsum[tid >> 6] = ss;
    __syncthreads();
    if (tid == 0) {
        float tot = wsum[0] + wsum[1] + wsum[2] + wsum[3];
        scale_sh = rsqrtf(tot * (1.0f / C_DIM) + 1e-6f) * premul;
    }
    __syncthreads();
    float scale = scale_sh;

    int t  = s / (HH * WW);
    int rm = s % (HH * WW);
    int hh = rm / WW, ww = rm % WW;

    float e[3][2];
    int cols[3];
    for (int i = 0; i < 3; ++i) {
        int p = tid + 256 * i;
        int j = p & 63;
        int col0 = (p >> 6) * DHEAD + 2 * j;
        cols[i] = col0;
        float e0 = bf2f(row[col0])     * scale * bf2f(g[col0]);
        float e1 = bf2f(row[col0 + 1]) * scale * bf2f(g[col0 + 1]);
        float pos, fr;
        if (j < 22)       { pos = (float)t;  fr = (float)j        * (1.0f / 22.0f); }
        else if (j < 43)  { pos = (float)hh; fr = (float)(j - 22) * (1.0f / 21.0f); }
        else              { pos = (float)ww; fr = (float)(j - 43) * (1.0f / 21.0f); }
        float ang = pos * expf(fr * -9.210340371976184f);
        float c = cosf(ang), sn = sinf(ang);
        e[i][0] = e0 * c - e1 * sn;
        e[i][1] = e0 * sn + e1 * c;
    }
    for (int i = 0; i < 3; ++i) {
        row[cols[i]]     = f2bf(e[i][0]);
        row[cols[i] + 1] = f2bf(e[i][1]);
    }
}

// ---------------- MFMA flash attention v8 ------------------------------
// v7 + shuffle-free common-path softmax: defer test uses the PER-LANE
// partial max (equivalent decision: __all over wave covers all lanes);
// l_run is a per-lane partial sum, cross-lane combined ONCE after the
// k-loop (valid: m_run stays quad-uniform -- it only changes on the
// rare non-defer path, where the full 2-shuffle quad reduce runs).
// Explicit max/add trees (no -ffast-math -> compiler can't reassociate).
// Steady-state tile: ZERO cross-lane ops in softmax.
__global__ __launch_bounds__(256, 2) void attn_mfma(const unsigned short* __restrict__ q,
                                                    const unsigned short* __restrict__ kp,
                                                    const unsigned short* __restrict__ vt,
                                                    unsigned short* __restrict__ o) {
    __shared__ __align__(16) unsigned char Ks[2][16384];  // 16 grp x 4key x 256B (swz)
    __shared__ __align__(16) unsigned char Vs[2][16384];  // 128 d x 128B keys (swz)
    __shared__ __align__(16) unsigned char Ps[8192];      // 4 waves x 16q x 128B (swz)

    int bid = xcd_swz(blockIdx.x, NHEAD * NKT);
    int h  = bid / NKT;
    int qt = bid % NKT;
    int q0 = qt * 64;
    int tid = threadIdx.x;
    int wave = tid >> 6, lane = tid & 63;
    int lm = lane & 15, lq = lane >> 4;

    // Q as B-operand fragments (lane = q-col, regs = d); pre-scaled by qsc
    bf16x8 qf[4];
    {
        int qr = q0 + wave * 16 + lm; if (qr >= S_TOT) qr = S_TOT - 1;
        const unsigned short* qptr = q + (size_t)qr * C_DIM + h * DHEAD + lq * 8;
        #pragma unroll
        for (int kc = 0; kc < 4; ++kc) qf[kc] = *(const bf16x8*)(qptr + kc * 32);
    }

    // K DMA: group = 4 keys x 128d (1KB); write chunk lane&15, swz by key&7
    int krow = lane >> 4;
    int kcolA = ((lane & 15) ^ krow) * 8;
    int kcolB = ((lane & 15) ^ (4 + krow)) * 8;
    // V DMA: group = 8 d-rows x 64 keys (1KB); key-slot swz by d&7
    int vr8 = lane >> 3;
    int vslot = (lane & 7) ^ vr8;

    int sxor = (lm & 7) << 4;            // read-side xor (key&7 / d&7 / q&7 = lm&7)
    int ksoff[4], kqoff[4];
    #pragma unroll
    for (int nt = 0; nt < 4; ++nt) ksoff[nt] = (nt * 4 + (lm >> 2)) * 1024 + (lm & 3) * 256;
    #pragma unroll
    for (int kc = 0; kc < 4; ++kc) kqoff[kc] = (kc * 4 + lq) * 16;

    f32x4 oacc[8];
    #pragma unroll
    for (int i = 0; i < 8; ++i) oacc[i] = (f32x4){0.f, 0.f, 0.f, 0.f};
    float m_run = -__builtin_inff();   // quad-uniform running max
    float l_run = 0.f;                 // PER-LANE partial sum

#define STAGE_KV(BUF, KT) do {                                              \
        int k0s = (KT) * 64;                                                \
        int vcol = k0s + vslot * 8; if (vcol > S_TOT - 8) vcol = S_TOT - 8; \
        _Pragma("unroll")                                                   \
        for (int t = 0; t < 4; ++t) {                                       \
            int g = wave * 4 + t;                                           \
            int grow = k0s + g * 4 + krow; if (grow > S_TOT - 1) grow = S_TOT - 1; \
            async16(kp + (size_t)grow * C_DIM + h * DHEAD + ((t & 1) ? kcolB : kcolA), \
                    Ks[BUF] + g * 1024);                                    \
            async16(vt + (size_t)(h * DHEAD + g * 8 + vr8) * S_TOT + vcol,  \
                    Vs[BUF] + g * 1024);                                    \
        } } while (0)

    STAGE_KV(0, 0);
    __syncthreads();                   // prologue drain
    int cur = 0;

    for (int kt = 0; kt < NKT; ++kt) {
        int k0 = kt * 64;
        if (kt + 1 < NKT) STAGE_KV(cur ^ 1, kt + 1);   // prefetch next tile
        const unsigned char* Kc = Ks[cur];
        const unsigned char* Vc = Vs[cur];

        // S^T[key][q]: sacc[nt] covers keys nt*16.., cols = q
        f32x4 sacc[4];
        #pragma unroll
        for (int nt = 0; nt < 4; ++nt) sacc[nt] = (f32x4){0.f, 0.f, 0.f, 0.f};
        #pragma unroll
        for (int kc = 0; kc < 4; ++kc)
            #pragma unroll
            for (int nt = 0; nt < 4; ++nt) {
                bf16x8 kf = *(const bf16x8*)(Kc + ((ksoff[nt] + kqoff[kc]) ^ sxor));
                sacc[nt] = __builtin_amdgcn_mfma_f32_16x16x32_bf16(kf, qf[kc], sacc[nt], 0, 0, 0);
            }
        // mask tail keys
        if (kt == NKT - 1) {
            #pragma unroll
            for (int nt = 0; nt < 4; ++nt)
                #pragma unroll
                for (int r = 0; r < 4; ++r)
                    if (k0 + nt * 16 + lq * 4 + r >= S_TOT) sacc[nt][r] = -__builtin_inff();
        }
        // --- softmax, base-2, quad-uniform m_run, per-lane partial l ---
        // per-lane max over this lane's 16 keys (explicit tree)
        float mtr[4];
        #pragma unroll
        for (int nt = 0; nt < 4; ++nt)
            mtr[nt] = fmaxf(fmaxf(sacc[nt][0], sacc[nt][1]),
                            fmaxf(sacc[nt][2], sacc[nt][3]));
        float pmax = fmaxf(fmaxf(mtr[0], mtr[1]), fmaxf(mtr[2], mtr[3]));
        // defer decision on PARTIAL maxima (wave-wide __all covers every
        // lane, so "no lane exceeds" == "no quad's true max exceeds")
        int defer = __all(pmax - m_run <= 8.0f);
        if (!defer) {
            float rmax = fmaxf(pmax, __shfl_xor(pmax, 16, 64));
            rmax = fmaxf(rmax, __shfl_xor(rmax, 32, 64));   // quad max
            float mn = fmaxf(m_run, rmax);
            float alpha = fexp2(m_run - mn);
            l_run *= alpha;
            #pragma unroll
            for (int i = 0; i < 8; ++i)
                #pragma unroll
                for (int r = 0; r < 4; ++r) oacc[i][r] *= alpha;
            m_run = mn;
        }
        // p = exp2(s - m_run); per-lane partial sum (tree)
        float rsn[4];
        #pragma unroll
        for (int nt = 0; nt < 4; ++nt) {
            float p0 = fexp2(sacc[nt][0] - m_run);
            float p1 = fexp2(sacc[nt][1] - m_run);
            float p2 = fexp2(sacc[nt][2] - m_run);
            float p3 = fexp2(sacc[nt][3] - m_run);
            sacc[nt][0] = p0; sacc[nt][1] = p1;
            sacc[nt][2] = p2; sacc[nt][3] = p3;
            rsn[nt] = (p0 + p1) + (p2 + p3);
        }
        l_run += (rsn[0] + rsn[1]) + (rsn[2] + rsn[3]);
        // P^T -> per-wave LDS (swz): row q=lm, keys nt*16+lq*4..
        #pragma unroll
        for (int nt = 0; nt < 4; ++nt) {
            uint2 pk;
            pk.x = pk2_trunc(sacc[nt][0], sacc[nt][1]);
            pk.y = pk2_trunc(sacc[nt][2], sacc[nt][3]);
            *(uint2*)(Ps + ((wave * 2048 + lm * 128 + nt * 32 + lq * 8) ^ sxor)) = pk;
        }
        // PV: O^T[d][q] += V^T[d][key] * P^T[key][q]
        #pragma unroll
        for (int kc = 0; kc < 2; ++kc) {
            bf16x8 pf = *(const bf16x8*)(Ps + ((wave * 2048 + lm * 128 + kc * 64 + lq * 16) ^ sxor));
            #pragma unroll
            for (int mt = 0; mt < 8; ++mt) {
                bf16x8 vf = *(const bf16x8*)(Vc + ((((mt * 16 + lm) * 128) + kc * 64 + lq * 16) ^ sxor));
                oacc[mt] = __builtin_amdgcn_mfma_f32_16x16x32_bf16(vf, pf, oacc[mt], 0, 0, 0);
            }
        }
        __syncthreads();               // next tile staged + this tile's reads done
        cur ^= 1;
    }
#undef STAGE_KV
    // combine per-lane partial l across the quad (ONCE, not per tile)
    l_run += __shfl_xor(l_run, 16, 64);
    l_run += __shfl_xor(l_run, 32, 64);
    // epilogue: lane owns q-column; d runs over mt/lq/r -> ushort4 stores
    int qrow = q0 + wave * 16 + lm;
    if (qrow < S_TOT) {
        float inv = 1.0f / l_run;
        #pragma unroll
        for (int mt = 0; mt < 8; ++mt) {
            ushort4 pk;
            pk.x = f2bf(oacc[mt][0] * inv);
            pk.y = f2bf(oacc[mt][1] * inv);
            pk.z = f2bf(oacc[mt][2] * inv);
            pk.w = f2bf(oacc[mt][3] * inv);
            *(ushort4*)(o + (size_t)qrow * C_DIM + h * DHEAD + mt * 16 + lq * 4) = pk;
        }
    }
}

// ------ Residual + transpose (S,C) bf16 -> (C,S) out (dual dtype) -----
__global__ __launch_bounds__(256) void resid_t(const unsigned short* __restrict__ proj,
                                               const void* __restrict__ x,
                                               const int* __restrict__ flag,
                                               void* __restrict__ out) {
    int isf32 = *flag;
    __shared__ float tile[32][33];
    int s0 = blockIdx.x * 32, c0 = blockIdx.y * 32;
    int tx = threadIdx.x, ty = threadIdx.y;   // (32,8)
    for (int r = 0; r < 4; ++r) {
        int sl = ty + 8 * r;
        tile[sl][tx] = bf2f(proj[(size_t)(s0 + sl) * C_DIM + (c0 + tx)]);
    }
    __syncthreads();
    for (int r = 0; r < 4; ++r) {
        int cl = ty + 8 * r;
        size_t idx = (size_t)(c0 + cl) * S_TOT + (s0 + tx);
        float val = ldin(x, idx, isf32) + tile[tx][cl];
        if (isf32) ((float*)out)[idx] = val;
        else       ((unsigned short*)out)[idx] = f2bf(val);
    }
}

extern "C" void kernel_launch(void* const* d_in, const int* in_sizes, int n_in,
                              void* d_out, int out_size, void* d_ws, size_t ws_size,
                              hipStream_t stream) {
    const void* x  = d_in[0];
    const void* Wq = d_in[1];
    const void* bq = d_in[2];
    const void* Wk = d_in[3];
    const void* bk = d_in[4];
    const void* Wv = d_in[5];
    const void* bv = d_in[6];
    const void* Wo = d_in[7];
    const void* bo = d_in[8];
    const void* gq = d_in[9];
    const void* gk = d_in[10];

    // ws ~55 MB: xn 11.9 | qb 11.9 | kb 11.9 | Ws0..3 18.9 | small
    char* ws = (char*)d_ws;
    size_t off = 0;
    auto alloc = [&](size_t bytes) -> char* {
        char* p = ws + off;
        off += (bytes + 255) & ~(size_t)255;
        return p;
    };
    const size_t SC = (size_t)S_TOT * C_DIM;
    const size_t WSZ = (size_t)C_DIM * C_DIM * 2;   // 4718592, 256B-aligned
    unsigned short* xn   = (unsigned short*)alloc(SC * 2);
    unsigned short* qb   = (unsigned short*)alloc(SC * 2);
    unsigned short* kb   = (unsigned short*)alloc(SC * 2);
    unsigned short* Ws0  = (unsigned short*)alloc(WSZ);  // Wq (stack head)
    unsigned short* Ws1  = (unsigned short*)alloc(WSZ);  // Wk (contiguous)
    unsigned short* Ws2  = (unsigned short*)alloc(WSZ);  // Wv (contiguous)
    unsigned short* Ws3  = (unsigned short*)alloc(WSZ);  // Wo
    unsigned short* vecs = (unsigned short*)alloc((size_t)6 * C_DIM * 2);
    float* meanb         = (float*)alloc((size_t)S_TOT * 4);
    float* rstdb         = (float*)alloc((size_t)S_TOT * 4);
    int*   flag          = (int*)alloc(256);
    unsigned short* Vt   = (unsigned short*)d_out;   // [C][S] scratch in d_out
    unsigned short* ob   = xn;   // alias (xn dead after QKV-GEMM)
    unsigned short* proj = qb;   // alias (qb dead after attn)

    (void)Ws1; (void)Ws2;   // accessed via the Ws0 stacked view in gemm2p

    // vecs layout: bq|bk|bv|bo|gq|gk  -> vecs[0..4607] = stacked QKV bias
    unsigned short* bo_b = vecs + 3 * C_DIM;
    unsigned short* gq_b = vecs + 4 * C_DIM;
    unsigned short* gk_b = vecs + 5 * C_DIM;

    const float QSC = 0.12751745f;   // 1/sqrt(128) * log2(e)

    dim3 t328(32, 8);
    dim3 tgrid(S_TOT / 32, C_DIM / 32);             // (121, 48)
    dim3 qkvgrid(31, 36);                           // 1116 blocks, N=4608
    dim3 ogrid(31, 24);                             // 744 blocks, N=1536
    dim3 wgrid((C_DIM * C_DIM) / 2048, 4);          // (1152, 4)
    dim3 rgrid(S_TOT, 2);

    detect_vecs<<<1, 256, 0, stream>>>((const unsigned short*)x, bq, bk, bv, bo, gq, gk, flag, vecs);
    wconv4<<<wgrid, 256, 0, stream>>>(Wq, Wk, Wv, Wo, flag, Ws0, Ws1, Ws2, Ws3);
    ln_stats<<<NKT, 256, 0, stream>>>(x, flag, meanb, rstdb);
    ln_norm_t<<<tgrid, t328, 0, stream>>>(x, flag, meanb, rstdb, xn);

    // fused QKV GEMM: N=4608 (Ws0 = stacked Wq|Wk|Wv), Q->qb, K->kb,
    // V->Vt (transposed [C][S])
    gemm2p<128><<<qkvgrid, 256, 0, stream>>>(xn, Ws0, vecs, qb, kb, Vt, C_DIM, 2 * C_DIM);
    rope2<<<rgrid, 256, 0, stream>>>(qb, kb, gq_b, gk_b, QSC);

    attn_mfma<<<NHEAD * NKT, 256, 0, stream>>>(qb, kb, Vt, ob);

    gemm2p<64><<<ogrid, 256, 0, stream>>>(ob, Ws3, bo_b, proj, proj, proj, 1 << 30, 1 << 30);
    resid_t<<<tgrid, t328, 0, stream>>>(proj, x, flag, d_out);
}

// Round 8
// 499.987 us; speedup vs baseline: 1.3044x; 1.2652x over previous
//
#include <hip/hip_runtime.h>

#define S_TOT 3872
#define C_DIM 1536
#define NHEAD 12
#define DHEAD 128
#define TT 8
#define HH 22
#define WW 22
#define NKT 61          // ceil(3872/64)   attn q tiles / ln grid x
#define NKT2 31         // ceil(3872/128)  attn key tiles (128-wide)

typedef __bf16 bf16x8 __attribute__((ext_vector_type(8)));
typedef float  f32x4  __attribute__((ext_vector_type(4)));
typedef unsigned short u16x8 __attribute__((ext_vector_type(8)));

__device__ __forceinline__ float bf2f(unsigned short u) {
    unsigned int v = ((unsigned int)u) << 16;
    float f; __builtin_memcpy(&f, &v, 4); return f;
}
__device__ __forceinline__ unsigned short f2bf(float f) {
    unsigned int u; __builtin_memcpy(&u, &f, 4);
    u += 0x7fffu + ((u >> 16) & 1u);
    return (unsigned short)(u >> 16);
}
// truncation-pack two f32 -> bf16x2 dword (internal P only; 1-ulp bias ok)
__device__ __forceinline__ unsigned int pk2_trunc(float a, float b) {
    unsigned int ua, ub;
    __builtin_memcpy(&ua, &a, 4); __builtin_memcpy(&ub, &b, 4);
    return (ua >> 16) | (ub & 0xffff0000u);
}
__device__ __forceinline__ float ldin(const void* p, size_t i, int isf32) {
    if (isf32) return ((const float*)p)[i];
    return bf2f(((const unsigned short*)p)[i]);
}
__device__ __forceinline__ float fexp2(float x) {
#if __has_builtin(__builtin_amdgcn_exp2f)
    return __builtin_amdgcn_exp2f(x);
#else
    return exp2f(x);
#endif
}
__device__ __forceinline__ void async16(const void* g, void* l) {
    __builtin_amdgcn_global_load_lds(
        (const __attribute__((address_space(1))) unsigned int*)g,
        (__attribute__((address_space(3))) unsigned int*)l, 16, 0, 0);
}
// bijective XCD-aware block remap (m204): chunk the grid across 8 XCDs
__device__ __forceinline__ int xcd_swz(int bid, int nwg) {
    int q = nwg >> 3, r = nwg & 7;
    int xcd = bid & 7, i = bid >> 3;
    int base = (xcd < r) ? xcd * (q + 1) : r * (q + 1) + (xcd - r) * q;
    return base + i;
}

// ------- dtype detector + bias/gain conversion + stat zeroing ---------
__global__ void detect_vecs(const unsigned short* __restrict__ x,
                            const void* p0, const void* p1, const void* p2,
                            const void* p3, const void* p4, const void* p5,
                            int* __restrict__ flag, unsigned short* __restrict__ vecs,
                            float* __restrict__ sumb, float* __restrict__ sumsqb) {
    __shared__ int cnt;
    if (threadIdx.x == 0) cnt = 0;
    __syncthreads();
    int c = 0;
    for (int i = 0; i < 8; ++i) {
        unsigned short u = x[threadIdx.x * 8 + i];
        int e = (u >> 7) & 0xFF;
        if (e >= 112 && e <= 143) c++;
    }
    atomicAdd(&cnt, c);
    // zero LN accumulators (ln_stats atomicAdds into them)
    for (int j = threadIdx.x; j < S_TOT; j += 256) {
        sumb[j] = 0.f; sumsqb[j] = 0.f;
    }
    __syncthreads();
    int isf32 = (cnt >= 1900) ? 0 : 1;
    if (threadIdx.x == 0) *flag = isf32;
    const void* ps[6] = {p0, p1, p2, p3, p4, p5};
    for (int v = 0; v < 6; ++v)
        for (int j = threadIdx.x; j < C_DIM; j += 256)
            vecs[v * C_DIM + j] = f2bf(ldin(ps[v], j, isf32));
}

// -------- four weight matrices -> bf16, grid (1152, 4) ----------------
__global__ __launch_bounds__(256) void wconv4(const void* __restrict__ s0,
                                              const void* __restrict__ s1,
                                              const void* __restrict__ s2,
                                              const void* __restrict__ s3,
                                              const int* __restrict__ flag,
                                              unsigned short* __restrict__ d0,
                                              unsigned short* __restrict__ d1,
                                              unsigned short* __restrict__ d2,
                                              unsigned short* __restrict__ d3) {
    const void* srcs[4] = {s0, s1, s2, s3};
    unsigned short* dsts[4] = {d0, d1, d2, d3};
    const void* src = srcs[blockIdx.y];
    unsigned short* dst = dsts[blockIdx.y];
    size_t i = ((size_t)blockIdx.x * 256 + threadIdx.x) * 8;
    if (*flag) {
        const float* s = (const float*)src + i;
        float4 a = *(const float4*)s, b = *(const float4*)(s + 4);
        u16x8 o;
        o[0]=f2bf(a.x); o[1]=f2bf(a.y); o[2]=f2bf(a.z); o[3]=f2bf(a.w);
        o[4]=f2bf(b.x); o[5]=f2bf(b.y); o[6]=f2bf(b.z); o[7]=f2bf(b.w);
        *(u16x8*)(dst + i) = o;
    } else {
        *(u16x8*)(dst + i) = *(const u16x8*)((const unsigned short*)src + i);
    }
}

// -------- LayerNorm partial stats: grid (61,4), block (64 s x 4 cg) ---
// Each block-y covers 384 channels; partial sums atomicAdd'd into
// sumb/sumsqb (zeroed by detect_vecs). 244 blocks vs old 61.
__global__ __launch_bounds__(256) void ln_stats(const void* __restrict__ x,
                                                const int* __restrict__ flag,
                                                float* __restrict__ sumb,
                                                float* __restrict__ sumsqb) {
    int isf32 = *flag;
    int sl = threadIdx.x & 63, cg = threadIdx.x >> 6;
    int s = blockIdx.x * 64 + sl;
    int cbase = blockIdx.y * 384;
    float sum = 0.f, sumsq = 0.f;
    if (s < S_TOT) {
        for (int c = cbase + cg; c < cbase + 384; c += 4) {
            float v = ldin(x, (size_t)c * S_TOT + s, isf32);
            sum += v; sumsq += v * v;
        }
    }
    __shared__ float r0[4][64], r1[4][64];
    r0[cg][sl] = sum; r1[cg][sl] = sumsq;
    __syncthreads();
    if (cg == 0 && s < S_TOT) {
        float st = r0[0][sl] + r0[1][sl] + r0[2][sl] + r0[3][sl];
        float sq = r1[0][sl] + r1[1][sl] + r1[2][sl] + r1[3][sl];
        atomicAdd(&sumb[s], st);
        atomicAdd(&sumsqb[s], sq);
    }
}

// ------------- Normalize + transpose (C,S) -> (S,C) bf16 --------------
// Finalizes stats inline from raw sums (cheap: 4 rsqrt per thread).
__global__ __launch_bounds__(256) void ln_norm_t(const void* __restrict__ x,
                                                 const int* __restrict__ flag,
                                                 const float* __restrict__ sumb,
                                                 const float* __restrict__ sumsqb,
                                                 unsigned short* __restrict__ xn) {
    int isf32 = *flag;
    __shared__ float tile[32][33];
    int s0 = blockIdx.x * 32, c0 = blockIdx.y * 32;
    int tx = threadIdx.x, ty = threadIdx.y;   // (32,8)
    for (int r = 0; r < 4; ++r) {
        int cl = ty + 8 * r;
        tile[cl][tx] = ldin(x, (size_t)(c0 + cl) * S_TOT + (s0 + tx), isf32);
    }
    __syncthreads();
    for (int r = 0; r < 4; ++r) {
        int sl = ty + 8 * r;
        int s = s0 + sl, c = c0 + tx;
        float m = sumb[s] * (1.0f / C_DIM);
        float var = sumsqb[s] * (1.0f / C_DIM) - m * m;
        float rstd = rsqrtf(var + 1e-6f);
        xn[(size_t)s * C_DIM + c] = f2bf((tile[tx][sl] - m) * rstd);
    }
}

// ------- MFMA GEMM, T3+T4: 128xBN tile, BK=32, dbuf LDS, COUNTED ------
// vmcnt + RAW barriers (m218 pattern). Unchanged from R7 (passed).
template<int BN>
__global__ __launch_bounds__(256, 3) void gemm2p(const unsigned short* __restrict__ A,
                                                 const unsigned short* __restrict__ W,
                                                 const unsigned short* __restrict__ bias,
                                                 unsigned short* __restrict__ D0,
                                                 unsigned short* __restrict__ D1,
                                                 unsigned short* __restrict__ DT,
                                                 int nsplit, int ntrans) {
    constexpr int NGRP = 8 + BN / 16;          // 1KB DMA groups per K-step
    constexpr int GPW  = NGRP / 4;             // groups per wave = loads/thread
    __shared__ __align__(16) unsigned short As[2][128 * 32];
    __shared__ __align__(16) unsigned short Bs[2][BN * 32];
    int nwg = gridDim.x * gridDim.y;
    int wg  = xcd_swz(blockIdx.y * gridDim.x + blockIdx.x, nwg);
    int m0 = (wg % gridDim.x) * 128, n0 = (wg / gridDim.x) * BN;
    int tid = threadIdx.x;
    int wave = tid >> 6, lane = tid & 63;
    int lm = lane & 15, lq = lane >> 4;
    int wr = wave >> 1, wc = wave & 1;
    int srow = lane >> 2, scol = (lane & 3) * 8;

    f32x4 acc[4][BN / 32];
    #pragma unroll
    for (int a = 0; a < 4; ++a)
        #pragma unroll
        for (int b = 0; b < BN / 32; ++b) acc[a][b] = (f32x4){0.f, 0.f, 0.f, 0.f};

    // prologue: stage k0=0 into buf 0 (stays in flight until loop's vmcnt)
    #pragma unroll
    for (int t = 0; t < GPW; ++t) {
        int g = wave * GPW + t;
        if (g < 8) {
            int am = m0 + g * 16 + srow; if (am > S_TOT - 1) am = S_TOT - 1;
            async16(A + (size_t)am * C_DIM + scol, (char*)As[0] + g * 1024);
        } else {
            int bn = n0 + (g - 8) * 16 + srow;
            async16(W + (size_t)bn * C_DIM + scol, (char*)Bs[0] + (g - 8) * 1024);
        }
    }
    int cur = 0;
    for (int k0 = 0; k0 < C_DIM; k0 += 32) {
        int kn = k0 + 32;
        if (kn < C_DIM) {
            #pragma unroll
            for (int t = 0; t < GPW; ++t) {
                int g = wave * GPW + t;
                if (g < 8) {
                    int am = m0 + g * 16 + srow; if (am > S_TOT - 1) am = S_TOT - 1;
                    async16(A + (size_t)am * C_DIM + kn + scol, (char*)As[cur ^ 1] + g * 1024);
                } else {
                    int bn = n0 + (g - 8) * 16 + srow;
                    async16(W + (size_t)bn * C_DIM + kn + scol, (char*)Bs[cur ^ 1] + (g - 8) * 1024);
                }
            }
            // wait only the PREVIOUS stage (GPW newest stay in flight)
            asm volatile("s_waitcnt vmcnt(%0)" :: "i"(GPW) : "memory");
        } else {
            asm volatile("s_waitcnt vmcnt(0)" ::: "memory");
        }
        __builtin_amdgcn_sched_barrier(0);
        __builtin_amdgcn_s_barrier();          // all waves' prev stage landed
        __builtin_amdgcn_sched_barrier(0);

        bf16x8 af[4], bf[BN / 32];
        #pragma unroll
        for (int mb = 0; mb < 4; ++mb)
            af[mb] = *(const bf16x8*)((const char*)As[cur] + (wr * 64 + mb * 16 + lm) * 64 + lq * 16);
        #pragma unroll
        for (int nb = 0; nb < BN / 32; ++nb)
            bf[nb] = *(const bf16x8*)((const char*)Bs[cur] + (wc * (BN / 2) + nb * 16 + lm) * 64 + lq * 16);
        #pragma unroll
        for (int mb = 0; mb < 4; ++mb)
            #pragma unroll
            for (int nb = 0; nb < BN / 32; ++nb)
                acc[mb][nb] = __builtin_amdgcn_mfma_f32_16x16x32_bf16(af[mb], bf[nb], acc[mb][nb], 0, 0, 0);

        __builtin_amdgcn_sched_barrier(0);
        __builtin_amdgcn_s_barrier();          // reads done; buf free to overwrite
        __builtin_amdgcn_sched_barrier(0);
        cur ^= 1;
    }

    #pragma unroll
    for (int mb = 0; mb < 4; ++mb) {
        #pragma unroll
        for (int nb = 0; nb < BN / 32; ++nb) {
            int gn = n0 + wc * (BN / 2) + nb * 16 + lm;
            float bv = bf2f(bias[gn]);
            if (gn >= ntrans) {          // transposed dest (V path)
                int gm0 = m0 + wr * 64 + mb * 16 + lq * 4;
                if (gm0 < S_TOT) {
                    ushort4 pk;
                    pk.x = f2bf(acc[mb][nb][0] + bv);
                    pk.y = f2bf(acc[mb][nb][1] + bv);
                    pk.z = f2bf(acc[mb][nb][2] + bv);
                    pk.w = f2bf(acc[mb][nb][3] + bv);
                    *(ushort4*)(DT + (size_t)(gn - ntrans) * S_TOT + gm0) = pk;
                }
            } else {                     // row-major, split between D0/D1
                unsigned short* dst = (gn < nsplit) ? D0 : D1;
                int cn = (gn < nsplit) ? gn : gn - nsplit;
                #pragma unroll
                for (int r = 0; r < 4; ++r) {
                    int gm = m0 + wr * 64 + mb * 16 + lq * 4 + r;
                    if (gm < S_TOT) dst[(size_t)gm * C_DIM + cn] = f2bf(acc[mb][nb][r] + bv);
                }
            }
        }
    }
}

// ---------- RMSNorm + RoPE for Q and K in one launch, in-place --------
__global__ __launch_bounds__(256) void rope2(unsigned short* __restrict__ qbuf,
                                             unsigned short* __restrict__ kbuf,
                                             const unsigned short* __restrict__ gq,
                                             const unsigned short* __restrict__ gk,
                                             float qsc) {
    int s = blockIdx.x;
    unsigned short* row = (blockIdx.y ? kbuf : qbuf) + (size_t)s * C_DIM;
    const unsigned short* g = blockIdx.y ? gk : gq;
    float premul = blockIdx.y ? 1.0f : qsc;
    int tid = threadIdx.x;
    float ss = 0.f;
    for (int i = 0; i < 6; ++i) {
        float v = bf2f(row[tid + 256 * i]);
        ss += v * v;
    }
    for (int off = 32; off; off >>= 1) ss += __shfl_down(ss, off, 64);
    __shared__ float wsum[4];
    __shared__ float scale_sh;
    if ((tid & 63) == 0) wsum[tid >> 6] = ss;
    __syncthreads();
    if (tid == 0) {
        float tot = wsum[0] + wsum[1] + wsum[2] + wsum[3];
        scale_sh = rsqrtf(tot * (1.0f / C_DIM) + 1e-6f) * premul;
    }
    __syncthreads();
    float scale = scale_sh;

    int t  = s / (HH * WW);
    int rm = s % (HH * WW);
    int hh = rm / WW, ww = rm % WW;

    float e[3][2];
    int cols[3];
    for (int i = 0; i < 3; ++i) {
        int p = tid + 256 * i;
        int j = p & 63;
        int col0 = (p >> 6) * DHEAD + 2 * j;
        cols[i] = col0;
        float e0 = bf2f(row[col0])     * scale * bf2f(g[col0]);
        float e1 = bf2f(row[col0 + 1]) * scale * bf2f(g[col0 + 1]);
        float pos, fr;
        if (j < 22)       { pos = (float)t;  fr = (float)j        * (1.0f / 22.0f); }
        else if (j < 43)  { pos = (float)hh; fr = (float)(j - 22) * (1.0f / 21.0f); }
        else              { pos = (float)ww; fr = (float)(j - 43) * (1.0f / 21.0f); }
        float ang = pos * expf(fr * -9.210340371976184f);
        float c = cosf(ang), sn = sinf(ang);
        e[i][0] = e0 * c - e1 * sn;
        e[i][1] = e0 * sn + e1 * c;
    }
    for (int i = 0; i < 3; ++i) {
        row[cols[i]]     = f2bf(e[i][0]);
        row[cols[i] + 1] = f2bf(e[i][1]);
    }
}

// ---------------- MFMA flash attention v9: KVBLK=128 ------------------
// 128-key tiles, single-buffered (R3 proved staging exposure ~free):
// halves per-tile fixed costs (62 barriers vs 122, half the stage-issue
// sequences and defer checks) at identical MFMA/LDS work per key.
// LDS 32+32+16 = 80KB -> 2 blocks/CU (same as v8's 72KB).
// K rows (256B) swizzled by key&7 (verified floor); V/P rows (256B)
// swizzled by full row&15 (4-bit field over 16 slots, <=2-way by calc).
__global__ __launch_bounds__(256, 2) void attn_mfma(const unsigned short* __restrict__ q,
                                                    const unsigned short* __restrict__ kp,
                                                    const unsigned short* __restrict__ vt,
                                                    unsigned short* __restrict__ o) {
    __shared__ __align__(16) unsigned char Ks[32768];  // 128 keys x 256B (swz key&7)
    __shared__ __align__(16) unsigned char Vs[32768];  // 128 d x 256B keys (swz d&15)
    __shared__ __align__(16) unsigned char Ps[16384];  // 4 waves x 16q x 256B (swz q&15)

    int bid = xcd_swz(blockIdx.x, NHEAD * NKT);
    int h  = bid / NKT;
    int qt = bid % NKT;
    int q0 = qt * 64;
    int tid = threadIdx.x;
    int wave = tid >> 6, lane = tid & 63;
    int lm = lane & 15, lq = lane >> 4;

    // Q as B-operand fragments (lane = q-col, regs = d); pre-scaled by qsc
    bf16x8 qf[4];
    {
        int qr = q0 + wave * 16 + lm; if (qr >= S_TOT) qr = S_TOT - 1;
        const unsigned short* qptr = q + (size_t)qr * C_DIM + h * DHEAD + lq * 8;
        #pragma unroll
        for (int kc = 0; kc < 4; ++kc) qf[kc] = *(const bf16x8*)(qptr + kc * 32);
    }

    // K DMA: 32 groups (4 keys x 128 d = 1KB); lane -> key lane>>4,
    // 16B chunk lane&15 swizzled by key&7 = (g&1)*4 + (lane>>4)
    int krow = lane >> 4;
    int kcolA = ((lane & 15) ^ krow) * 8;
    int kcolB = ((lane & 15) ^ (4 + krow)) * 8;
    // V DMA: 32 groups (4 d-rows x 128 keys = 1KB); lane -> d-row lane>>4,
    // key-slot lane&15 swizzled by d&15 = (g&3)*4 + (lane>>4)
    int vdr = lane >> 4;

    int sxor  = (lm & 7) << 4;           // K read xor (key&7 = lm&7)
    int psxor = lm << 4;                 // V/P read xor (row&15 = lm)
    int ksoff[8], kqoff[4];
    #pragma unroll
    for (int nt = 0; nt < 8; ++nt) ksoff[nt] = (nt * 4 + (lm >> 2)) * 1024 + (lm & 3) * 256;
    #pragma unroll
    for (int kc = 0; kc < 4; ++kc) kqoff[kc] = (kc * 4 + lq) * 16;

    f32x4 oacc[8];
    #pragma unroll
    for (int i = 0; i < 8; ++i) oacc[i] = (f32x4){0.f, 0.f, 0.f, 0.f};
    float m_run = -__builtin_inff();   // quad-uniform running max
    float l_run = 0.f;                 // per-lane partial sum

    for (int kt = 0; kt < NKT2; ++kt) {
        int k0 = kt * 128;
        // stage K: 8 groups per wave
        #pragma unroll
        for (int t = 0; t < 8; ++t) {
            int g = wave * 8 + t;
            int grow = k0 + g * 4 + krow; if (grow > S_TOT - 1) grow = S_TOT - 1;
            async16(kp + (size_t)grow * C_DIM + h * DHEAD + ((t & 1) ? kcolB : kcolA),
                    Ks + g * 1024);
        }
        // stage V: 8 groups per wave
        #pragma unroll
        for (int t = 0; t < 8; ++t) {
            int g = wave * 8 + t;
            int vslot = (lane & 15) ^ ((g & 3) * 4 + vdr);
            int vcol = k0 + vslot * 8; if (vcol > S_TOT - 8) vcol = S_TOT - 8;
            async16(vt + (size_t)(h * DHEAD + g * 4 + vdr) * S_TOT + vcol,
                    Vs + g * 1024);
        }
        __syncthreads();               // DMA drained, LDS visible

        // S^T[key][q]: sacc[nt] covers keys nt*16.., cols = q
        f32x4 sacc[8];
        #pragma unroll
        for (int nt = 0; nt < 8; ++nt) sacc[nt] = (f32x4){0.f, 0.f, 0.f, 0.f};
        #pragma unroll
        for (int kc = 0; kc < 4; ++kc)
            #pragma unroll
            for (int nt = 0; nt < 8; ++nt) {
                bf16x8 kf = *(const bf16x8*)(Ks + ((ksoff[nt] + kqoff[kc]) ^ sxor));
                sacc[nt] = __builtin_amdgcn_mfma_f32_16x16x32_bf16(kf, qf[kc], sacc[nt], 0, 0, 0);
            }
        // mask tail keys (only last tile partial: 30*128=3840 < 3872)
        if (kt == NKT2 - 1) {
            #pragma unroll
            for (int nt = 0; nt < 8; ++nt)
                #pragma unroll
                for (int r = 0; r < 4; ++r)
                    if (k0 + nt * 16 + lq * 4 + r >= S_TOT) sacc[nt][r] = -__builtin_inff();
        }
        // --- softmax, base-2, quad-uniform m_run, per-lane partial l ---
        float mtr[8];
        #pragma unroll
        for (int nt = 0; nt < 8; ++nt)
            mtr[nt] = fmaxf(fmaxf(sacc[nt][0], sacc[nt][1]),
                            fmaxf(sacc[nt][2], sacc[nt][3]));
        float pmax = fmaxf(fmaxf(fmaxf(mtr[0], mtr[1]), fmaxf(mtr[2], mtr[3])),
                           fmaxf(fmaxf(mtr[4], mtr[5]), fmaxf(mtr[6], mtr[7])));
        int defer = __all(pmax - m_run <= 8.0f);
        if (!defer) {
            float rmax = fmaxf(pmax, __shfl_xor(pmax, 16, 64));
            rmax = fmaxf(rmax, __shfl_xor(rmax, 32, 64));   // quad max
            float mn = fmaxf(m_run, rmax);
            float alpha = fexp2(m_run - mn);
            l_run *= alpha;
            #pragma unroll
            for (int i = 0; i < 8; ++i)
                #pragma unroll
                for (int r = 0; r < 4; ++r) oacc[i][r] *= alpha;
            m_run = mn;
        }
        float rtot = 0.f;
        #pragma unroll
        for (int nt = 0; nt < 8; ++nt) {
            float p0 = fexp2(sacc[nt][0] - m_run);
            float p1 = fexp2(sacc[nt][1] - m_run);
            float p2 = fexp2(sacc[nt][2] - m_run);
            float p3 = fexp2(sacc[nt][3] - m_run);
            sacc[nt][0] = p0; sacc[nt][1] = p1;
            sacc[nt][2] = p2; sacc[nt][3] = p3;
            rtot += (p0 + p1) + (p2 + p3);
        }
        l_run += rtot;
        // P^T -> per-wave LDS (swz): row q=lm, logical byte = key*2
        #pragma unroll
        for (int nt = 0; nt < 8; ++nt) {
            uint2 pk;
            pk.x = pk2_trunc(sacc[nt][0], sacc[nt][1]);
            pk.y = pk2_trunc(sacc[nt][2], sacc[nt][3]);
            *(uint2*)(Ps + (wave * 4096 + lm * 256 + ((nt * 32 + lq * 8) ^ psxor))) = pk;
        }
        // PV: O^T[d][q] += V^T[d][key] * P^T[key][q]; kc = 32-key slices
        #pragma unroll
        for (int kc = 0; kc < 4; ++kc) {
            bf16x8 pf = *(const bf16x8*)(Ps + (wave * 4096 + lm * 256 + ((kc * 64 + lq * 16) ^ psxor)));
            #pragma unroll
            for (int mt = 0; mt < 8; ++mt) {
                bf16x8 vf = *(const bf16x8*)(Vs + ((mt * 16 + lm) * 256 + ((kc * 64 + lq * 16) ^ psxor)));
                oacc[mt] = __builtin_amdgcn_mfma_f32_16x16x32_bf16(vf, pf, oacc[mt], 0, 0, 0);
            }
        }
        __syncthreads();               // reads done before next stage overwrite
    }
    // combine per-lane partial l across the quad (ONCE, not per tile)
    l_run += __shfl_xor(l_run, 16, 64);
    l_run += __shfl_xor(l_run, 32, 64);
    // epilogue: lane owns q-column; d runs over mt/lq/r -> ushort4 stores
    int qrow = q0 + wave * 16 + lm;
    if (qrow < S_TOT) {
        float inv = 1.0f / l_run;
        #pragma unroll
        for (int mt = 0; mt < 8; ++mt) {
            ushort4 pk;
            pk.x = f2bf(oacc[mt][0] * inv);
            pk.y = f2bf(oacc[mt][1] * inv);
            pk.z = f2bf(oacc[mt][2] * inv);
            pk.w = f2bf(oacc[mt][3] * inv);
            *(ushort4*)(o + (size_t)qrow * C_DIM + h * DHEAD + mt * 16 + lq * 4) = pk;
        }
    }
}

// ------ Residual + transpose (S,C) bf16 -> (C,S) out (dual dtype) -----
__global__ __launch_bounds__(256) void resid_t(const unsigned short* __restrict__ proj,
                                               const void* __restrict__ x,
                                               const int* __restrict__ flag,
                                               void* __restrict__ out) {
    int isf32 = *flag;
    __shared__ float tile[32][33];
    int s0 = blockIdx.x * 32, c0 = blockIdx.y * 32;
    int tx = threadIdx.x, ty = threadIdx.y;   // (32,8)
    for (int r = 0; r < 4; ++r) {
        int sl = ty + 8 * r;
        tile[sl][tx] = bf2f(proj[(size_t)(s0 + sl) * C_DIM + (c0 + tx)]);
    }
    __syncthreads();
    for (int r = 0; r < 4; ++r) {
        int cl = ty + 8 * r;
        size_t idx = (size_t)(c0 + cl) * S_TOT + (s0 + tx);
        float val = ldin(x, idx, isf32) + tile[tx][cl];
        if (isf32) ((float*)out)[idx] = val;
        else       ((unsigned short*)out)[idx] = f2bf(val);
    }
}

extern "C" void kernel_launch(void* const* d_in, const int* in_sizes, int n_in,
                              void* d_out, int out_size, void* d_ws, size_t ws_size,
                              hipStream_t stream) {
    const void* x  = d_in[0];
    const void* Wq = d_in[1];
    const void* bq = d_in[2];
    const void* Wk = d_in[3];
    const void* bk = d_in[4];
    const void* Wv = d_in[5];
    const void* bv = d_in[6];
    const void* Wo = d_in[7];
    const void* bo = d_in[8];
    const void* gq = d_in[9];
    const void* gk = d_in[10];

    // ws ~55 MB: xn 11.9 | qb 11.9 | kb 11.9 | Ws0..3 18.9 | small
    char* ws = (char*)d_ws;
    size_t off = 0;
    auto alloc = [&](size_t bytes) -> char* {
        char* p = ws + off;
        off += (bytes + 255) & ~(size_t)255;
        return p;
    };
    const size_t SC = (size_t)S_TOT * C_DIM;
    const size_t WSZ = (size_t)C_DIM * C_DIM * 2;   // 4718592, 256B-aligned
    unsigned short* xn   = (unsigned short*)alloc(SC * 2);
    unsigned short* qb   = (unsigned short*)alloc(SC * 2);
    unsigned short* kb   = (unsigned short*)alloc(SC * 2);
    unsigned short* Ws0  = (unsigned short*)alloc(WSZ);  // Wq (stack head)
    unsigned short* Ws1  = (unsigned short*)alloc(WSZ);  // Wk (contiguous)
    unsigned short* Ws2  = (unsigned short*)alloc(WSZ);  // Wv (contiguous)
    unsigned short* Ws3  = (unsigned short*)alloc(WSZ);  // Wo
    unsigned short* vecs = (unsigned short*)alloc((size_t)6 * C_DIM * 2);
    float* sumb          = (float*)alloc((size_t)S_TOT * 4);
    float* sumsqb        = (float*)alloc((size_t)S_TOT * 4);
    int*   flag          = (int*)alloc(256);
    unsigned short* Vt   = (unsigned short*)d_out;   // [C][S] scratch in d_out
    unsigned short* ob   = xn;   // alias (xn dead after QKV-GEMM)
    unsigned short* proj = qb;   // alias (qb dead after attn)

    (void)Ws1; (void)Ws2;   // accessed via the Ws0 stacked view in gemm2p

    // vecs layout: bq|bk|bv|bo|gq|gk  -> vecs[0..4607] = stacked QKV bias
    unsigned short* bo_b = vecs + 3 * C_DIM;
    unsigned short* gq_b = vecs + 4 * C_DIM;
    unsigned short* gk_b = vecs + 5 * C_DIM;

    const float QSC = 0.12751745f;   // 1/sqrt(128) * log2(e)

    dim3 t328(32, 8);
    dim3 tgrid(S_TOT / 32, C_DIM / 32);             // (121, 48)
    dim3 qkvgrid(31, 36);                           // 1116 blocks, N=4608
    dim3 ogrid(31, 24);                             // 744 blocks, N=1536
    dim3 wgrid((C_DIM * C_DIM) / 2048, 4);          // (1152, 4)
    dim3 sgrid(NKT, 4);                             // (61, 4) ln partials
    dim3 rgrid(S_TOT, 2);

    detect_vecs<<<1, 256, 0, stream>>>((const unsigned short*)x, bq, bk, bv, bo, gq, gk,
                                       flag, vecs, sumb, sumsqb);
    wconv4<<<wgrid, 256, 0, stream>>>(Wq, Wk, Wv, Wo, flag, Ws0, Ws1, Ws2, Ws3);
    ln_stats<<<sgrid, 256, 0, stream>>>(x, flag, sumb, sumsqb);
    ln_norm_t<<<tgrid, t328, 0, stream>>>(x, flag, sumb, sumsqb, xn);

    // fused QKV GEMM: N=4608 (Ws0 = stacked Wq|Wk|Wv), Q->qb, K->kb,
    // V->Vt (transposed [C][S])
    gemm2p<128><<<qkvgrid, 256, 0, stream>>>(xn, Ws0, vecs, qb, kb, Vt, C_DIM, 2 * C_DIM);
    rope2<<<rgrid, 256, 0, stream>>>(qb, kb, gq_b, gk_b, QSC);

    attn_mfma<<<NHEAD * NKT, 256, 0, stream>>>(qb, kb, Vt, ob);

    gemm2p<64><<<ogrid, 256, 0, stream>>>(ob, Ws3, bo_b, proj, proj, proj, 1 << 30, 1 << 30);
    resid_t<<<tgrid, t328, 0, stream>>>(proj, x, flag, d_out);
}

// Round 9
// 484.782 us; speedup vs baseline: 1.3453x; 1.0314x over previous
//
#include <hip/hip_runtime.h>

#define S_TOT 3872
#define C_DIM 1536
#define NHEAD 12
#define DHEAD 128
#define TT 8
#define HH 22
#define WW 22
#define NKT 61          // ceil(3872/64)   attn q tiles / ln grid x
#define NKT2 31         // ceil(3872/128)  attn key tiles (128-wide)

typedef __bf16 bf16x8 __attribute__((ext_vector_type(8)));
typedef float  f32x4  __attribute__((ext_vector_type(4)));
typedef unsigned short u16x8 __attribute__((ext_vector_type(8)));

__device__ __forceinline__ float bf2f(unsigned short u) {
    unsigned int v = ((unsigned int)u) << 16;
    float f; __builtin_memcpy(&f, &v, 4); return f;
}
__device__ __forceinline__ unsigned short f2bf(float f) {
    unsigned int u; __builtin_memcpy(&u, &f, 4);
    u += 0x7fffu + ((u >> 16) & 1u);
    return (unsigned short)(u >> 16);
}
// truncation-pack two f32 -> bf16x2 dword (internal P only; 1-ulp bias ok)
__device__ __forceinline__ unsigned int pk2_trunc(float a, float b) {
    unsigned int ua, ub;
    __builtin_memcpy(&ua, &a, 4); __builtin_memcpy(&ub, &b, 4);
    return (ua >> 16) | (ub & 0xffff0000u);
}
__device__ __forceinline__ float ldin(const void* p, size_t i, int isf32) {
    if (isf32) return ((const float*)p)[i];
    return bf2f(((const unsigned short*)p)[i]);
}
__device__ __forceinline__ float fexp2(float x) {
#if __has_builtin(__builtin_amdgcn_exp2f)
    return __builtin_amdgcn_exp2f(x);
#else
    return exp2f(x);
#endif
}
__device__ __forceinline__ void async16(const void* g, void* l) {
    __builtin_amdgcn_global_load_lds(
        (const __attribute__((address_space(1))) unsigned int*)g,
        (__attribute__((address_space(3))) unsigned int*)l, 16, 0, 0);
}
// bijective XCD-aware block remap (m204): chunk the grid across 8 XCDs
__device__ __forceinline__ int xcd_swz(int bid, int nwg) {
    int q = nwg >> 3, r = nwg & 7;
    int xcd = bid & 7, i = bid >> 3;
    int base = (xcd < r) ? xcd * (q + 1) : r * (q + 1) + (xcd - r) * q;
    return base + i;
}

// ------- dtype detector + bias/gain conversion + stat zeroing ---------
__global__ void detect_vecs(const unsigned short* __restrict__ x,
                            const void* p0, const void* p1, const void* p2,
                            const void* p3, const void* p4, const void* p5,
                            int* __restrict__ flag, unsigned short* __restrict__ vecs,
                            float* __restrict__ sumb, float* __restrict__ sumsqb) {
    __shared__ int cnt;
    if (threadIdx.x == 0) cnt = 0;
    __syncthreads();
    int c = 0;
    for (int i = 0; i < 8; ++i) {
        unsigned short u = x[threadIdx.x * 8 + i];
        int e = (u >> 7) & 0xFF;
        if (e >= 112 && e <= 143) c++;
    }
    atomicAdd(&cnt, c);
    // zero LN accumulators (ln_stats atomicAdds into them)
    for (int j = threadIdx.x; j < S_TOT; j += 256) {
        sumb[j] = 0.f; sumsqb[j] = 0.f;
    }
    __syncthreads();
    int isf32 = (cnt >= 1900) ? 0 : 1;
    if (threadIdx.x == 0) *flag = isf32;
    const void* ps[6] = {p0, p1, p2, p3, p4, p5};
    for (int v = 0; v < 6; ++v)
        for (int j = threadIdx.x; j < C_DIM; j += 256)
            vecs[v * C_DIM + j] = f2bf(ldin(ps[v], j, isf32));
}

// -------- four weight matrices -> bf16, grid (1152, 4) ----------------
__global__ __launch_bounds__(256) void wconv4(const void* __restrict__ s0,
                                              const void* __restrict__ s1,
                                              const void* __restrict__ s2,
                                              const void* __restrict__ s3,
                                              const int* __restrict__ flag,
                                              unsigned short* __restrict__ d0,
                                              unsigned short* __restrict__ d1,
                                              unsigned short* __restrict__ d2,
                                              unsigned short* __restrict__ d3) {
    const void* srcs[4] = {s0, s1, s2, s3};
    unsigned short* dsts[4] = {d0, d1, d2, d3};
    const void* src = srcs[blockIdx.y];
    unsigned short* dst = dsts[blockIdx.y];
    size_t i = ((size_t)blockIdx.x * 256 + threadIdx.x) * 8;
    if (*flag) {
        const float* s = (const float*)src + i;
        float4 a = *(const float4*)s, b = *(const float4*)(s + 4);
        u16x8 o;
        o[0]=f2bf(a.x); o[1]=f2bf(a.y); o[2]=f2bf(a.z); o[3]=f2bf(a.w);
        o[4]=f2bf(b.x); o[5]=f2bf(b.y); o[6]=f2bf(b.z); o[7]=f2bf(b.w);
        *(u16x8*)(dst + i) = o;
    } else {
        *(u16x8*)(dst + i) = *(const u16x8*)((const unsigned short*)src + i);
    }
}

// -------- LayerNorm partial stats: grid (61,4), block (64 s x 4 cg) ---
__global__ __launch_bounds__(256) void ln_stats(const void* __restrict__ x,
                                                const int* __restrict__ flag,
                                                float* __restrict__ sumb,
                                                float* __restrict__ sumsqb) {
    int isf32 = *flag;
    int sl = threadIdx.x & 63, cg = threadIdx.x >> 6;
    int s = blockIdx.x * 64 + sl;
    int cbase = blockIdx.y * 384;
    float sum = 0.f, sumsq = 0.f;
    if (s < S_TOT) {
        for (int c = cbase + cg; c < cbase + 384; c += 4) {
            float v = ldin(x, (size_t)c * S_TOT + s, isf32);
            sum += v; sumsq += v * v;
        }
    }
    __shared__ float r0[4][64], r1[4][64];
    r0[cg][sl] = sum; r1[cg][sl] = sumsq;
    __syncthreads();
    if (cg == 0 && s < S_TOT) {
        float st = r0[0][sl] + r0[1][sl] + r0[2][sl] + r0[3][sl];
        float sq = r1[0][sl] + r1[1][sl] + r1[2][sl] + r1[3][sl];
        atomicAdd(&sumb[s], st);
        atomicAdd(&sumsqb[s], sq);
    }
}

// ------------- Normalize + transpose (C,S) -> (S,C) bf16 --------------
__global__ __launch_bounds__(256) void ln_norm_t(const void* __restrict__ x,
                                                 const int* __restrict__ flag,
                                                 const float* __restrict__ sumb,
                                                 const float* __restrict__ sumsqb,
                                                 unsigned short* __restrict__ xn) {
    int isf32 = *flag;
    __shared__ float tile[32][33];
    int s0 = blockIdx.x * 32, c0 = blockIdx.y * 32;
    int tx = threadIdx.x, ty = threadIdx.y;   // (32,8)
    for (int r = 0; r < 4; ++r) {
        int cl = ty + 8 * r;
        tile[cl][tx] = ldin(x, (size_t)(c0 + cl) * S_TOT + (s0 + tx), isf32);
    }
    __syncthreads();
    for (int r = 0; r < 4; ++r) {
        int sl = ty + 8 * r;
        int s = s0 + sl, c = c0 + tx;
        float m = sumb[s] * (1.0f / C_DIM);
        float var = sumsqb[s] * (1.0f / C_DIM) - m * m;
        float rstd = rsqrtf(var + 1e-6f);
        xn[(size_t)s * C_DIM + c] = f2bf((tile[tx][sl] - m) * rstd);
    }
}

// ------- MFMA GEMM, T3+T4: 128xBN tile, BK=32, dbuf LDS, COUNTED ------
// vmcnt + RAW barriers (m218 pattern). BN=192 for QKV: 24 MFMA / 10
// ds_reads per wave-K-step (vs 16/8), grid 31x24=744 balanced 2.9/CU.
template<int BN>
__global__ __launch_bounds__(256, 3) void gemm2p(const unsigned short* __restrict__ A,
                                                 const unsigned short* __restrict__ W,
                                                 const unsigned short* __restrict__ bias,
                                                 unsigned short* __restrict__ D0,
                                                 unsigned short* __restrict__ D1,
                                                 unsigned short* __restrict__ DT,
                                                 int nsplit, int ntrans) {
    constexpr int NGRP = 8 + BN / 16;          // 1KB DMA groups per K-step
    constexpr int GPW  = NGRP / 4;             // groups per wave = loads/thread
    __shared__ __align__(16) unsigned short As[2][128 * 32];
    __shared__ __align__(16) unsigned short Bs[2][BN * 32];
    int nwg = gridDim.x * gridDim.y;
    int wg  = xcd_swz(blockIdx.y * gridDim.x + blockIdx.x, nwg);
    int m0 = (wg % gridDim.x) * 128, n0 = (wg / gridDim.x) * BN;
    int tid = threadIdx.x;
    int wave = tid >> 6, lane = tid & 63;
    int lm = lane & 15, lq = lane >> 4;
    int wr = wave >> 1, wc = wave & 1;
    int srow = lane >> 2, scol = (lane & 3) * 8;

    f32x4 acc[4][BN / 32];
    #pragma unroll
    for (int a = 0; a < 4; ++a)
        #pragma unroll
        for (int b = 0; b < BN / 32; ++b) acc[a][b] = (f32x4){0.f, 0.f, 0.f, 0.f};

    // prologue: stage k0=0 into buf 0 (stays in flight until loop's vmcnt)
    #pragma unroll
    for (int t = 0; t < GPW; ++t) {
        int g = wave * GPW + t;
        if (g < 8) {
            int am = m0 + g * 16 + srow; if (am > S_TOT - 1) am = S_TOT - 1;
            async16(A + (size_t)am * C_DIM + scol, (char*)As[0] + g * 1024);
        } else {
            int bn = n0 + (g - 8) * 16 + srow;
            async16(W + (size_t)bn * C_DIM + scol, (char*)Bs[0] + (g - 8) * 1024);
        }
    }
    int cur = 0;
    for (int k0 = 0; k0 < C_DIM; k0 += 32) {
        int kn = k0 + 32;
        if (kn < C_DIM) {
            #pragma unroll
            for (int t = 0; t < GPW; ++t) {
                int g = wave * GPW + t;
                if (g < 8) {
                    int am = m0 + g * 16 + srow; if (am > S_TOT - 1) am = S_TOT - 1;
                    async16(A + (size_t)am * C_DIM + kn + scol, (char*)As[cur ^ 1] + g * 1024);
                } else {
                    int bn = n0 + (g - 8) * 16 + srow;
                    async16(W + (size_t)bn * C_DIM + kn + scol, (char*)Bs[cur ^ 1] + (g - 8) * 1024);
                }
            }
            // wait only the PREVIOUS stage (GPW newest stay in flight)
            asm volatile("s_waitcnt vmcnt(%0)" :: "i"(GPW) : "memory");
        } else {
            asm volatile("s_waitcnt vmcnt(0)" ::: "memory");
        }
        __builtin_amdgcn_sched_barrier(0);
        __builtin_amdgcn_s_barrier();          // all waves' prev stage landed
        __builtin_amdgcn_sched_barrier(0);

        bf16x8 af[4], bf[BN / 32];
        #pragma unroll
        for (int mb = 0; mb < 4; ++mb)
            af[mb] = *(const bf16x8*)((const char*)As[cur] + (wr * 64 + mb * 16 + lm) * 64 + lq * 16);
        #pragma unroll
        for (int nb = 0; nb < BN / 32; ++nb)
            bf[nb] = *(const bf16x8*)((const char*)Bs[cur] + (wc * (BN / 2) + nb * 16 + lm) * 64 + lq * 16);
        #pragma unroll
        for (int mb = 0; mb < 4; ++mb)
            #pragma unroll
            for (int nb = 0; nb < BN / 32; ++nb)
                acc[mb][nb] = __builtin_amdgcn_mfma_f32_16x16x32_bf16(af[mb], bf[nb], acc[mb][nb], 0, 0, 0);

        __builtin_amdgcn_sched_barrier(0);
        __builtin_amdgcn_s_barrier();          // reads done; buf free to overwrite
        __builtin_amdgcn_sched_barrier(0);
        cur ^= 1;
    }

    #pragma unroll
    for (int mb = 0; mb < 4; ++mb) {
        #pragma unroll
        for (int nb = 0; nb < BN / 32; ++nb) {
            int gn = n0 + wc * (BN / 2) + nb * 16 + lm;
            float bv = bf2f(bias[gn]);
            if (gn >= ntrans) {          // transposed dest (V path)
                int gm0 = m0 + wr * 64 + mb * 16 + lq * 4;
                if (gm0 < S_TOT) {
                    ushort4 pk;
                    pk.x = f2bf(acc[mb][nb][0] + bv);
                    pk.y = f2bf(acc[mb][nb][1] + bv);
                    pk.z = f2bf(acc[mb][nb][2] + bv);
                    pk.w = f2bf(acc[mb][nb][3] + bv);
                    *(ushort4*)(DT + (size_t)(gn - ntrans) * S_TOT + gm0) = pk;
                }
            } else {                     // row-major, split between D0/D1
                unsigned short* dst = (gn < nsplit) ? D0 : D1;
                int cn = (gn < nsplit) ? gn : gn - nsplit;
                #pragma unroll
                for (int r = 0; r < 4; ++r) {
                    int gm = m0 + wr * 64 + mb * 16 + lq * 4 + r;
                    if (gm < S_TOT) dst[(size_t)gm * C_DIM + cn] = f2bf(acc[mb][nb][r] + bv);
                }
            }
        }
    }
}

// ---------- RMSNorm + RoPE for Q and K in one launch, in-place --------
__global__ __launch_bounds__(256) void rope2(unsigned short* __restrict__ qbuf,
                                             unsigned short* __restrict__ kbuf,
                                             const unsigned short* __restrict__ gq,
                                             const unsigned short* __restrict__ gk,
                                             float qsc) {
    int s = blockIdx.x;
    unsigned short* row = (blockIdx.y ? kbuf : qbuf) + (size_t)s * C_DIM;
    const unsigned short* g = blockIdx.y ? gk : gq;
    float premul = blockIdx.y ? 1.0f : qsc;
    int tid = threadIdx.x;
    float ss = 0.f;
    for (int i = 0; i < 6; ++i) {
        float v = bf2f(row[tid + 256 * i]);
        ss += v * v;
    }
    for (int off = 32; off; off >>= 1) ss += __shfl_down(ss, off, 64);
    __shared__ float wsum[4];
    __shared__ float scale_sh;
    if ((tid & 63) == 0) wsum[tid >> 6] = ss;
    __syncthreads();
    if (tid == 0) {
        float tot = wsum[0] + wsum[1] + wsum[2] + wsum[3];
        scale_sh = rsqrtf(tot * (1.0f / C_DIM) + 1e-6f) * premul;
    }
    __syncthreads();
    float scale = scale_sh;

    int t  = s / (HH * WW);
    int rm = s % (HH * WW);
    int hh = rm / WW, ww = rm % WW;

    float e[3][2];
    int cols[3];
    for (int i = 0; i < 3; ++i) {
        int p = tid + 256 * i;
        int j = p & 63;
        int col0 = (p >> 6) * DHEAD + 2 * j;
        cols[i] = col0;
        float e0 = bf2f(row[col0])     * scale * bf2f(g[col0]);
        float e1 = bf2f(row[col0 + 1]) * scale * bf2f(g[col0 + 1]);
        float pos, fr;
        if (j < 22)       { pos = (float)t;  fr = (float)j        * (1.0f / 22.0f); }
        else if (j < 43)  { pos = (float)hh; fr = (float)(j - 22) * (1.0f / 21.0f); }
        else              { pos = (float)ww; fr = (float)(j - 43) * (1.0f / 21.0f); }
        float ang = pos * expf(fr * -9.210340371976184f);
        float c = cosf(ang), sn = sinf(ang);
        e[i][0] = e0 * c - e1 * sn;
        e[i][1] = e0 * sn + e1 * c;
    }
    for (int i = 0; i < 3; ++i) {
        row[cols[i]]     = f2bf(e[i][0]);
        row[cols[i] + 1] = f2bf(e[i][1]);
    }
}

// ---------------- MFMA flash attention v10: phase-pipelined staging ----
// K and V are consumed in different phases, so each 32KB buffer is idle
// half the tile: issue K(t+1) right after QK(t)'s reads complete, V(t+1)
// after PV(t). Gates: counted vmcnt(8) (own-wave) + raw s_barrier (era
// guarantee, m218 mechanism). Steady state: 16 loads in flight, never
// vmcnt(0) -> ~1100cy/tile L2 staging hides under softmax/PV/QK.
// Safety: every kf/vf value is consumed by an MFMA before the barrier
// (compiler lgkmcnt on the data dep), so raw barriers suffice; all
// barriers thread-uniform. LDS 80KB, unchanged.
__global__ __launch_bounds__(256, 2) void attn_mfma(const unsigned short* __restrict__ q,
                                                    const unsigned short* __restrict__ kp,
                                                    const unsigned short* __restrict__ vt,
                                                    unsigned short* __restrict__ o) {
    __shared__ __align__(16) unsigned char Ks[32768];  // 128 keys x 256B (swz key&7)
    __shared__ __align__(16) unsigned char Vs[32768];  // 128 d x 256B keys (swz d&15)
    __shared__ __align__(16) unsigned char Ps[16384];  // 4 waves x 16q x 256B (swz q&15)

    int bid = xcd_swz(blockIdx.x, NHEAD * NKT);
    int h  = bid / NKT;
    int qt = bid % NKT;
    int q0 = qt * 64;
    int tid = threadIdx.x;
    int wave = tid >> 6, lane = tid & 63;
    int lm = lane & 15, lq = lane >> 4;

    // Q as B-operand fragments (lane = q-col, regs = d); pre-scaled by qsc
    bf16x8 qf[4];
    {
        int qr = q0 + wave * 16 + lm; if (qr >= S_TOT) qr = S_TOT - 1;
        const unsigned short* qptr = q + (size_t)qr * C_DIM + h * DHEAD + lq * 8;
        #pragma unroll
        for (int kc = 0; kc < 4; ++kc) qf[kc] = *(const bf16x8*)(qptr + kc * 32);
    }

    // K DMA: 32 groups (4 keys x 128 d = 1KB); lane -> key lane>>4,
    // 16B chunk lane&15 swizzled by key&7 = (g&1)*4 + (lane>>4)
    int krow = lane >> 4;
    int kcolA = ((lane & 15) ^ krow) * 8;
    int kcolB = ((lane & 15) ^ (4 + krow)) * 8;
    // V DMA: 32 groups (4 d-rows x 128 keys = 1KB); lane -> d-row lane>>4,
    // key-slot lane&15 swizzled by d&15 = (g&3)*4 + (lane>>4)
    int vdr = lane >> 4;

    int sxor  = (lm & 7) << 4;           // K read xor (key&7 = lm&7)
    int psxor = lm << 4;                 // V/P read xor (row&15 = lm)
    int ksoff[8], kqoff[4];
    #pragma unroll
    for (int nt = 0; nt < 8; ++nt) ksoff[nt] = (nt * 4 + (lm >> 2)) * 1024 + (lm & 3) * 256;
    #pragma unroll
    for (int kc = 0; kc < 4; ++kc) kqoff[kc] = (kc * 4 + lq) * 16;

    f32x4 oacc[8];
    #pragma unroll
    for (int i = 0; i < 8; ++i) oacc[i] = (f32x4){0.f, 0.f, 0.f, 0.f};
    float m_run = -__builtin_inff();   // quad-uniform running max
    float l_run = 0.f;                 // per-lane partial sum

#define STAGE_K(KT) do {                                                    \
        int k0s = (KT) * 128;                                               \
        _Pragma("unroll")                                                   \
        for (int t = 0; t < 8; ++t) {                                       \
            int g = wave * 8 + t;                                           \
            int grow = k0s + g * 4 + krow; if (grow > S_TOT - 1) grow = S_TOT - 1; \
            async16(kp + (size_t)grow * C_DIM + h * DHEAD + ((t & 1) ? kcolB : kcolA), \
                    Ks + g * 1024);                                         \
        } } while (0)
#define STAGE_V(KT) do {                                                    \
        int k0s = (KT) * 128;                                               \
        _Pragma("unroll")                                                   \
        for (int t = 0; t < 8; ++t) {                                       \
            int g = wave * 8 + t;                                           \
            int vslot = (lane & 15) ^ ((g & 3) * 4 + vdr);                  \
            int vcol = k0s + vslot * 8; if (vcol > S_TOT - 8) vcol = S_TOT - 8; \
            async16(vt + (size_t)(h * DHEAD + g * 4 + vdr) * S_TOT + vcol,  \
                    Vs + g * 1024);                                         \
        } } while (0)
#define RAW_BARRIER() do {                                                  \
        __builtin_amdgcn_sched_barrier(0);                                  \
        __builtin_amdgcn_s_barrier();                                       \
        __builtin_amdgcn_sched_barrier(0);                                  \
    } while (0)

    STAGE_K(0);                        // outstanding: K(0)=8
    STAGE_V(0);                        // outstanding: K(0)=8, V(0)=8

    for (int kt = 0; kt < NKT2; ++kt) {
        int k0 = kt * 128;
        int ktn = (kt + 1 < NKT2) ? kt + 1 : NKT2 - 1;   // clamped prefetch

        // --- K(kt) ready gate: drain to 8 (V(kt) stays in flight) ---
        asm volatile("s_waitcnt vmcnt(8)" ::: "memory");
        RAW_BARRIER();

        // S^T[key][q]: sacc[nt] covers keys nt*16.., cols = q
        f32x4 sacc[8];
        #pragma unroll
        for (int nt = 0; nt < 8; ++nt) sacc[nt] = (f32x4){0.f, 0.f, 0.f, 0.f};
        #pragma unroll
        for (int kc = 0; kc < 4; ++kc)
            #pragma unroll
            for (int nt = 0; nt < 8; ++nt) {
                bf16x8 kf = *(const bf16x8*)(Ks + ((ksoff[nt] + kqoff[kc]) ^ sxor));
                sacc[nt] = __builtin_amdgcn_mfma_f32_16x16x32_bf16(kf, qf[kc], sacc[nt], 0, 0, 0);
            }

        // --- Kb reads done -> overwrite allowed ---
        RAW_BARRIER();
        STAGE_K(ktn);                  // outstanding: V(kt)=8 + K(kt+1)=8

        // mask tail keys (only last tile partial: 30*128=3840 < 3872)
        if (kt == NKT2 - 1) {
            #pragma unroll
            for (int nt = 0; nt < 8; ++nt)
                #pragma unroll
                for (int r = 0; r < 4; ++r)
                    if (k0 + nt * 16 + lq * 4 + r >= S_TOT) sacc[nt][r] = -__builtin_inff();
        }
        // --- softmax, base-2, quad-uniform m_run, per-lane partial l ---
        float mtr[8];
        #pragma unroll
        for (int nt = 0; nt < 8; ++nt)
            mtr[nt] = fmaxf(fmaxf(sacc[nt][0], sacc[nt][1]),
                            fmaxf(sacc[nt][2], sacc[nt][3]));
        float pmax = fmaxf(fmaxf(fmaxf(mtr[0], mtr[1]), fmaxf(mtr[2], mtr[3])),
                           fmaxf(fmaxf(mtr[4], mtr[5]), fmaxf(mtr[6], mtr[7])));
        int defer = __all(pmax - m_run <= 8.0f);
        if (!defer) {
            float rmax = fmaxf(pmax, __shfl_xor(pmax, 16, 64));
            rmax = fmaxf(rmax, __shfl_xor(rmax, 32, 64));   // quad max
            float mn = fmaxf(m_run, rmax);
            float alpha = fexp2(m_run - mn);
            l_run *= alpha;
            #pragma unroll
            for (int i = 0; i < 8; ++i)
                #pragma unroll
                for (int r = 0; r < 4; ++r) oacc[i][r] *= alpha;
            m_run = mn;
        }
        float rtot = 0.f;
        #pragma unroll
        for (int nt = 0; nt < 8; ++nt) {
            float p0 = fexp2(sacc[nt][0] - m_run);
            float p1 = fexp2(sacc[nt][1] - m_run);
            float p2 = fexp2(sacc[nt][2] - m_run);
            float p3 = fexp2(sacc[nt][3] - m_run);
            sacc[nt][0] = p0; sacc[nt][1] = p1;
            sacc[nt][2] = p2; sacc[nt][3] = p3;
            rtot += (p0 + p1) + (p2 + p3);
        }
        l_run += rtot;
        // P^T -> per-wave LDS (swz): row q=lm, logical byte = key*2
        #pragma unroll
        for (int nt = 0; nt < 8; ++nt) {
            uint2 pk;
            pk.x = pk2_trunc(sacc[nt][0], sacc[nt][1]);
            pk.y = pk2_trunc(sacc[nt][2], sacc[nt][3]);
            *(uint2*)(Ps + (wave * 4096 + lm * 256 + ((nt * 32 + lq * 8) ^ psxor))) = pk;
        }

        // --- V(kt) ready gate: drain to 8 (K(kt+1) stays in flight) ---
        asm volatile("s_waitcnt vmcnt(8)" ::: "memory");
        RAW_BARRIER();

        // PV: O^T[d][q] += V^T[d][key] * P^T[key][q]; kc = 32-key slices
        #pragma unroll
        for (int kc = 0; kc < 4; ++kc) {
            bf16x8 pf = *(const bf16x8*)(Ps + (wave * 4096 + lm * 256 + ((kc * 64 + lq * 16) ^ psxor)));
            #pragma unroll
            for (int mt = 0; mt < 8; ++mt) {
                bf16x8 vf = *(const bf16x8*)(Vs + ((mt * 16 + lm) * 256 + ((kc * 64 + lq * 16) ^ psxor)));
                oacc[mt] = __builtin_amdgcn_mfma_f32_16x16x32_bf16(vf, pf, oacc[mt], 0, 0, 0);
            }
        }

        // --- Vb reads done -> overwrite allowed ---
        RAW_BARRIER();
        STAGE_V(ktn);                  // outstanding: K(kt+1)=8 + V(kt+1)=8
    }
#undef STAGE_K
#undef STAGE_V
#undef RAW_BARRIER
    // combine per-lane partial l across the quad (ONCE, not per tile)
    l_run += __shfl_xor(l_run, 16, 64);
    l_run += __shfl_xor(l_run, 32, 64);
    // epilogue: lane owns q-column; d runs over mt/lq/r -> ushort4 stores
    int qrow = q0 + wave * 16 + lm;
    if (qrow < S_TOT) {
        float inv = 1.0f / l_run;
        #pragma unroll
        for (int mt = 0; mt < 8; ++mt) {
            ushort4 pk;
            pk.x = f2bf(oacc[mt][0] * inv);
            pk.y = f2bf(oacc[mt][1] * inv);
            pk.z = f2bf(oacc[mt][2] * inv);
            pk.w = f2bf(oacc[mt][3] * inv);
            *(ushort4*)(o + (size_t)qrow * C_DIM + h * DHEAD + mt * 16 + lq * 4) = pk;
        }
    }
}

// ------ Residual + transpose (S,C) bf16 -> (C,S) out (dual dtype) -----
__global__ __launch_bounds__(256) void resid_t(const unsigned short* __restrict__ proj,
                                               const void* __restrict__ x,
                                               const int* __restrict__ flag,
                                               void* __restrict__ out) {
    int isf32 = *flag;
    __shared__ float tile[32][33];
    int s0 = blockIdx.x * 32, c0 = blockIdx.y * 32;
    int tx = threadIdx.x, ty = threadIdx.y;   // (32,8)
    for (int r = 0; r < 4; ++r) {
        int sl = ty + 8 * r;
        tile[sl][tx] = bf2f(proj[(size_t)(s0 + sl) * C_DIM + (c0 + tx)]);
    }
    __syncthreads();
    for (int r = 0; r < 4; ++r) {
        int cl = ty + 8 * r;
        size_t idx = (size_t)(c0 + cl) * S_TOT + (s0 + tx);
        float val = ldin(x, idx, isf32) + tile[tx][cl];
        if (isf32) ((float*)out)[idx] = val;
        else       ((unsigned short*)out)[idx] = f2bf(val);
    }
}

extern "C" void kernel_launch(void* const* d_in, const int* in_sizes, int n_in,
                              void* d_out, int out_size, void* d_ws, size_t ws_size,
                              hipStream_t stream) {
    const void* x  = d_in[0];
    const void* Wq = d_in[1];
    const void* bq = d_in[2];
    const void* Wk = d_in[3];
    const void* bk = d_in[4];
    const void* Wv = d_in[5];
    const void* bv = d_in[6];
    const void* Wo = d_in[7];
    const void* bo = d_in[8];
    const void* gq = d_in[9];
    const void* gk = d_in[10];

    // ws ~55 MB: xn 11.9 | qb 11.9 | kb 11.9 | Ws0..3 18.9 | small
    char* ws = (char*)d_ws;
    size_t off = 0;
    auto alloc = [&](size_t bytes) -> char* {
        char* p = ws + off;
        off += (bytes + 255) & ~(size_t)255;
        return p;
    };
    const size_t SC = (size_t)S_TOT * C_DIM;
    const size_t WSZ = (size_t)C_DIM * C_DIM * 2;   // 4718592, 256B-aligned
    unsigned short* xn   = (unsigned short*)alloc(SC * 2);
    unsigned short* qb   = (unsigned short*)alloc(SC * 2);
    unsigned short* kb   = (unsigned short*)alloc(SC * 2);
    unsigned short* Ws0  = (unsigned short*)alloc(WSZ);  // Wq (stack head)
    unsigned short* Ws1  = (unsigned short*)alloc(WSZ);  // Wk (contiguous)
    unsigned short* Ws2  = (unsigned short*)alloc(WSZ);  // Wv (contiguous)
    unsigned short* Ws3  = (unsigned short*)alloc(WSZ);  // Wo
    unsigned short* vecs = (unsigned short*)alloc((size_t)6 * C_DIM * 2);
    float* sumb          = (float*)alloc((size_t)S_TOT * 4);
    float* sumsqb        = (float*)alloc((size_t)S_TOT * 4);
    int*   flag          = (int*)alloc(256);
    unsigned short* Vt   = (unsigned short*)d_out;   // [C][S] scratch in d_out
    unsigned short* ob   = xn;   // alias (xn dead after QKV-GEMM)
    unsigned short* proj = qb;   // alias (qb dead after attn)

    (void)Ws1; (void)Ws2;   // accessed via the Ws0 stacked view in gemm2p

    // vecs layout: bq|bk|bv|bo|gq|gk  -> vecs[0..4607] = stacked QKV bias
    unsigned short* bo_b = vecs + 3 * C_DIM;
    unsigned short* gq_b = vecs + 4 * C_DIM;
    unsigned short* gk_b = vecs + 5 * C_DIM;

    const float QSC = 0.12751745f;   // 1/sqrt(128) * log2(e)

    dim3 t328(32, 8);
    dim3 tgrid(S_TOT / 32, C_DIM / 32);             // (121, 48)
    dim3 qkvgrid(31, 24);                           // 744 blocks, N=4608 BN=192
    dim3 ogrid(31, 24);                             // 744 blocks, N=1536 BN=64
    dim3 wgrid((C_DIM * C_DIM) / 2048, 4);          // (1152, 4)
    dim3 sgrid(NKT, 4);                             // (61, 4) ln partials
    dim3 rgrid(S_TOT, 2);

    detect_vecs<<<1, 256, 0, stream>>>((const unsigned short*)x, bq, bk, bv, bo, gq, gk,
                                       flag, vecs, sumb, sumsqb);
    wconv4<<<wgrid, 256, 0, stream>>>(Wq, Wk, Wv, Wo, flag, Ws0, Ws1, Ws2, Ws3);
    ln_stats<<<sgrid, 256, 0, stream>>>(x, flag, sumb, sumsqb);
    ln_norm_t<<<tgrid, t328, 0, stream>>>(x, flag, sumb, sumsqb, xn);

    // fused QKV GEMM: N=4608 (Ws0 = stacked Wq|Wk|Wv), Q->qb, K->kb,
    // V->Vt (transposed [C][S])
    gemm2p<192><<<qkvgrid, 256, 0, stream>>>(xn, Ws0, vecs, qb, kb, Vt, C_DIM, 2 * C_DIM);
    rope2<<<rgrid, 256, 0, stream>>>(qb, kb, gq_b, gk_b, QSC);

    attn_mfma<<<NHEAD * NKT, 256, 0, stream>>>(qb, kb, Vt, ob);

    gemm2p<64><<<ogrid, 256, 0, stream>>>(ob, Ws3, bo_b, proj, proj, proj, 1 << 30, 1 << 30);
    resid_t<<<tgrid, t328, 0, stream>>>(proj, x, flag, d_out);
}

// Round 10
// 469.907 us; speedup vs baseline: 1.3879x; 1.0317x over previous
//
#include <hip/hip_runtime.h>

#define S_TOT 3872
#define C_DIM 1536
#define NHEAD 12
#define DHEAD 128
#define TT 8
#define HH 22
#define WW 22
#define NKT 61          // ceil(3872/64)   attn q tiles / ln grid x / attn key tiles

typedef __bf16 bf16x8 __attribute__((ext_vector_type(8)));
typedef float  f32x4  __attribute__((ext_vector_type(4)));
typedef unsigned short u16x8 __attribute__((ext_vector_type(8)));

__device__ __forceinline__ float bf2f(unsigned short u) {
    unsigned int v = ((unsigned int)u) << 16;
    float f; __builtin_memcpy(&f, &v, 4); return f;
}
__device__ __forceinline__ unsigned short f2bf(float f) {
    unsigned int u; __builtin_memcpy(&u, &f, 4);
    u += 0x7fffu + ((u >> 16) & 1u);
    return (unsigned short)(u >> 16);
}
// truncation-pack two f32 -> bf16x2 dword (internal P only; 1-ulp bias ok)
__device__ __forceinline__ unsigned int pk2_trunc(float a, float b) {
    unsigned int ua, ub;
    __builtin_memcpy(&ua, &a, 4); __builtin_memcpy(&ub, &b, 4);
    return (ua >> 16) | (ub & 0xffff0000u);
}
__device__ __forceinline__ float ldin(const void* p, size_t i, int isf32) {
    if (isf32) return ((const float*)p)[i];
    return bf2f(((const unsigned short*)p)[i]);
}
__device__ __forceinline__ float fexp2(float x) {
#if __has_builtin(__builtin_amdgcn_exp2f)
    return __builtin_amdgcn_exp2f(x);
#else
    return exp2f(x);
#endif
}
__device__ __forceinline__ void async16(const void* g, void* l) {
    __builtin_amdgcn_global_load_lds(
        (const __attribute__((address_space(1))) unsigned int*)g,
        (__attribute__((address_space(3))) unsigned int*)l, 16, 0, 0);
}
// bijective XCD-aware block remap (m204): chunk the grid across 8 XCDs
__device__ __forceinline__ int xcd_swz(int bid, int nwg) {
    int q = nwg >> 3, r = nwg & 7;
    int xcd = bid & 7, i = bid >> 3;
    int base = (xcd < r) ? xcd * (q + 1) : r * (q + 1) + (xcd - r) * q;
    return base + i;
}

// ------- dtype detector + bias/gain conversion + stat zeroing ---------
__global__ void detect_vecs(const unsigned short* __restrict__ x,
                            const void* p0, const void* p1, const void* p2,
                            const void* p3, const void* p4, const void* p5,
                            int* __restrict__ flag, unsigned short* __restrict__ vecs,
                            float* __restrict__ sumb, float* __restrict__ sumsqb) {
    __shared__ int cnt;
    if (threadIdx.x == 0) cnt = 0;
    __syncthreads();
    int c = 0;
    for (int i = 0; i < 8; ++i) {
        unsigned short u = x[threadIdx.x * 8 + i];
        int e = (u >> 7) & 0xFF;
        if (e >= 112 && e <= 143) c++;
    }
    atomicAdd(&cnt, c);
    // zero LN accumulators (ln_stats atomicAdds into them)
    for (int j = threadIdx.x; j < S_TOT; j += 256) {
        sumb[j] = 0.f; sumsqb[j] = 0.f;
    }
    __syncthreads();
    int isf32 = (cnt >= 1900) ? 0 : 1;
    if (threadIdx.x == 0) *flag = isf32;
    const void* ps[6] = {p0, p1, p2, p3, p4, p5};
    for (int v = 0; v < 6; ++v)
        for (int j = threadIdx.x; j < C_DIM; j += 256)
            vecs[v * C_DIM + j] = f2bf(ldin(ps[v], j, isf32));
}

// -------- four weight matrices -> bf16, grid (1152, 4) ----------------
__global__ __launch_bounds__(256) void wconv4(const void* __restrict__ s0,
                                              const void* __restrict__ s1,
                                              const void* __restrict__ s2,
                                              const void* __restrict__ s3,
                                              const int* __restrict__ flag,
                                              unsigned short* __restrict__ d0,
                                              unsigned short* __restrict__ d1,
                                              unsigned short* __restrict__ d2,
                                              unsigned short* __restrict__ d3) {
    const void* srcs[4] = {s0, s1, s2, s3};
    unsigned short* dsts[4] = {d0, d1, d2, d3};
    const void* src = srcs[blockIdx.y];
    unsigned short* dst = dsts[blockIdx.y];
    size_t i = ((size_t)blockIdx.x * 256 + threadIdx.x) * 8;
    if (*flag) {
        const float* s = (const float*)src + i;
        float4 a = *(const float4*)s, b = *(const float4*)(s + 4);
        u16x8 o;
        o[0]=f2bf(a.x); o[1]=f2bf(a.y); o[2]=f2bf(a.z); o[3]=f2bf(a.w);
        o[4]=f2bf(b.x); o[5]=f2bf(b.y); o[6]=f2bf(b.z); o[7]=f2bf(b.w);
        *(u16x8*)(dst + i) = o;
    } else {
        *(u16x8*)(dst + i) = *(const u16x8*)((const unsigned short*)src + i);
    }
}

// -------- LayerNorm partial stats: grid (61,4), block (64 s x 4 cg) ---
__global__ __launch_bounds__(256) void ln_stats(const void* __restrict__ x,
                                                const int* __restrict__ flag,
                                                float* __restrict__ sumb,
                                                float* __restrict__ sumsqb) {
    int isf32 = *flag;
    int sl = threadIdx.x & 63, cg = threadIdx.x >> 6;
    int s = blockIdx.x * 64 + sl;
    int cbase = blockIdx.y * 384;
    float sum = 0.f, sumsq = 0.f;
    if (s < S_TOT) {
        for (int c = cbase + cg; c < cbase + 384; c += 4) {
            float v = ldin(x, (size_t)c * S_TOT + s, isf32);
            sum += v; sumsq += v * v;
        }
    }
    __shared__ float r0[4][64], r1[4][64];
    r0[cg][sl] = sum; r1[cg][sl] = sumsq;
    __syncthreads();
    if (cg == 0 && s < S_TOT) {
        float st = r0[0][sl] + r0[1][sl] + r0[2][sl] + r0[3][sl];
        float sq = r1[0][sl] + r1[1][sl] + r1[2][sl] + r1[3][sl];
        atomicAdd(&sumb[s], st);
        atomicAdd(&sumsqb[s], sq);
    }
}

// ------------- Normalize + transpose (C,S) -> (S,C) bf16 --------------
__global__ __launch_bounds__(256) void ln_norm_t(const void* __restrict__ x,
                                                 const int* __restrict__ flag,
                                                 const float* __restrict__ sumb,
                                                 const float* __restrict__ sumsqb,
                                                 unsigned short* __restrict__ xn) {
    int isf32 = *flag;
    __shared__ float tile[32][33];
    int s0 = blockIdx.x * 32, c0 = blockIdx.y * 32;
    int tx = threadIdx.x, ty = threadIdx.y;   // (32,8)
    for (int r = 0; r < 4; ++r) {
        int cl = ty + 8 * r;
        tile[cl][tx] = ldin(x, (size_t)(c0 + cl) * S_TOT + (s0 + tx), isf32);
    }
    __syncthreads();
    for (int r = 0; r < 4; ++r) {
        int sl = ty + 8 * r;
        int s = s0 + sl, c = c0 + tx;
        float m = sumb[s] * (1.0f / C_DIM);
        float var = sumsqb[s] * (1.0f / C_DIM) - m * m;
        float rstd = rsqrtf(var + 1e-6f);
        xn[(size_t)s * C_DIM + c] = f2bf((tile[tx][sl] - m) * rstd);
    }
}

// ------- MFMA GEMM, T3+T4: 128xBN tile, BK=32, dbuf LDS, COUNTED ------
// vmcnt + RAW barriers (m218 pattern). Unchanged from R9 (passed).
template<int BN>
__global__ __launch_bounds__(256, 3) void gemm2p(const unsigned short* __restrict__ A,
                                                 const unsigned short* __restrict__ W,
                                                 const unsigned short* __restrict__ bias,
                                                 unsigned short* __restrict__ D0,
                                                 unsigned short* __restrict__ D1,
                                                 unsigned short* __restrict__ DT,
                                                 int nsplit, int ntrans) {
    constexpr int NGRP = 8 + BN / 16;          // 1KB DMA groups per K-step
    constexpr int GPW  = NGRP / 4;             // groups per wave = loads/thread
    __shared__ __align__(16) unsigned short As[2][128 * 32];
    __shared__ __align__(16) unsigned short Bs[2][BN * 32];
    int nwg = gridDim.x * gridDim.y;
    int wg  = xcd_swz(blockIdx.y * gridDim.x + blockIdx.x, nwg);
    int m0 = (wg % gridDim.x) * 128, n0 = (wg / gridDim.x) * BN;
    int tid = threadIdx.x;
    int wave = tid >> 6, lane = tid & 63;
    int lm = lane & 15, lq = lane >> 4;
    int wr = wave >> 1, wc = wave & 1;
    int srow = lane >> 2, scol = (lane & 3) * 8;

    f32x4 acc[4][BN / 32];
    #pragma unroll
    for (int a = 0; a < 4; ++a)
        #pragma unroll
        for (int b = 0; b < BN / 32; ++b) acc[a][b] = (f32x4){0.f, 0.f, 0.f, 0.f};

    // prologue: stage k0=0 into buf 0 (stays in flight until loop's vmcnt)
    #pragma unroll
    for (int t = 0; t < GPW; ++t) {
        int g = wave * GPW + t;
        if (g < 8) {
            int am = m0 + g * 16 + srow; if (am > S_TOT - 1) am = S_TOT - 1;
            async16(A + (size_t)am * C_DIM + scol, (char*)As[0] + g * 1024);
        } else {
            int bn = n0 + (g - 8) * 16 + srow;
            async16(W + (size_t)bn * C_DIM + scol, (char*)Bs[0] + (g - 8) * 1024);
        }
    }
    int cur = 0;
    for (int k0 = 0; k0 < C_DIM; k0 += 32) {
        int kn = k0 + 32;
        if (kn < C_DIM) {
            #pragma unroll
            for (int t = 0; t < GPW; ++t) {
                int g = wave * GPW + t;
                if (g < 8) {
                    int am = m0 + g * 16 + srow; if (am > S_TOT - 1) am = S_TOT - 1;
                    async16(A + (size_t)am * C_DIM + kn + scol, (char*)As[cur ^ 1] + g * 1024);
                } else {
                    int bn = n0 + (g - 8) * 16 + srow;
                    async16(W + (size_t)bn * C_DIM + kn + scol, (char*)Bs[cur ^ 1] + (g - 8) * 1024);
                }
            }
            // wait only the PREVIOUS stage (GPW newest stay in flight)
            asm volatile("s_waitcnt vmcnt(%0)" :: "i"(GPW) : "memory");
        } else {
            asm volatile("s_waitcnt vmcnt(0)" ::: "memory");
        }
        __builtin_amdgcn_sched_barrier(0);
        __builtin_amdgcn_s_barrier();          // all waves' prev stage landed
        __builtin_amdgcn_sched_barrier(0);

        bf16x8 af[4], bf[BN / 32];
        #pragma unroll
        for (int mb = 0; mb < 4; ++mb)
            af[mb] = *(const bf16x8*)((const char*)As[cur] + (wr * 64 + mb * 16 + lm) * 64 + lq * 16);
        #pragma unroll
        for (int nb = 0; nb < BN / 32; ++nb)
            bf[nb] = *(const bf16x8*)((const char*)Bs[cur] + (wc * (BN / 2) + nb * 16 + lm) * 64 + lq * 16);
        #pragma unroll
        for (int mb = 0; mb < 4; ++mb)
            #pragma unroll
            for (int nb = 0; nb < BN / 32; ++nb)
                acc[mb][nb] = __builtin_amdgcn_mfma_f32_16x16x32_bf16(af[mb], bf[nb], acc[mb][nb], 0, 0, 0);

        __builtin_amdgcn_sched_barrier(0);
        __builtin_amdgcn_s_barrier();          // reads done; buf free to overwrite
        __builtin_amdgcn_sched_barrier(0);
        cur ^= 1;
    }

    #pragma unroll
    for (int mb = 0; mb < 4; ++mb) {
        #pragma unroll
        for (int nb = 0; nb < BN / 32; ++nb) {
            int gn = n0 + wc * (BN / 2) + nb * 16 + lm;
            float bv = bf2f(bias[gn]);
            if (gn >= ntrans) {          // transposed dest (V path)
                int gm0 = m0 + wr * 64 + mb * 16 + lq * 4;
                if (gm0 < S_TOT) {
                    ushort4 pk;
                    pk.x = f2bf(acc[mb][nb][0] + bv);
                    pk.y = f2bf(acc[mb][nb][1] + bv);
                    pk.z = f2bf(acc[mb][nb][2] + bv);
                    pk.w = f2bf(acc[mb][nb][3] + bv);
                    *(ushort4*)(DT + (size_t)(gn - ntrans) * S_TOT + gm0) = pk;
                }
            } else {                     // row-major, split between D0/D1
                unsigned short* dst = (gn < nsplit) ? D0 : D1;
                int cn = (gn < nsplit) ? gn : gn - nsplit;
                #pragma unroll
                for (int r = 0; r < 4; ++r) {
                    int gm = m0 + wr * 64 + mb * 16 + lq * 4 + r;
                    if (gm < S_TOT) dst[(size_t)gm * C_DIM + cn] = f2bf(acc[mb][nb][r] + bv);
                }
            }
        }
    }
}

// ---------- RMSNorm + RoPE for Q and K in one launch, in-place --------
__global__ __launch_bounds__(256) void rope2(unsigned short* __restrict__ qbuf,
                                             unsigned short* __restrict__ kbuf,
                                             const unsigned short* __restrict__ gq,
                                             const unsigned short* __restrict__ gk,
                                             float qsc) {
    int s = blockIdx.x;
    unsigned short* row = (blockIdx.y ? kbuf : qbuf) + (size_t)s * C_DIM;
    const unsigned short* g = blockIdx.y ? gk : gq;
    float premul = blockIdx.y ? 1.0f : qsc;
    int tid = threadIdx.x;
    float ss = 0.f;
    for (int i = 0; i < 6; ++i) {
        float v = bf2f(row[tid + 256 * i]);
        ss += v * v;
    }
    for (int off = 32; off; off >>= 1) ss += __shfl_down(ss, off, 64);
    __shared__ float wsum[4];
    __shared__ float scale_sh;
    if ((tid & 63) == 0) wsum[tid >> 6] = ss;
    __syncthreads();
    if (tid == 0) {
        float tot = wsum[0] + wsum[1] + wsum[2] + wsum[3];
        scale_sh = rsqrtf(tot * (1.0f / C_DIM) + 1e-6f) * premul;
    }
    __syncthreads();
    float scale = scale_sh;

    int t  = s / (HH * WW);
    int rm = s % (HH * WW);
    int hh = rm / WW, ww = rm % WW;

    float e[3][2];
    int cols[3];
    for (int i = 0; i < 3; ++i) {
        int p = tid + 256 * i;
        int j = p & 63;
        int col0 = (p >> 6) * DHEAD + 2 * j;
        cols[i] = col0;
        float e0 = bf2f(row[col0])     * scale * bf2f(g[col0]);
        float e1 = bf2f(row[col0 + 1]) * scale * bf2f(g[col0 + 1]);
        float pos, fr;
        if (j < 22)       { pos = (float)t;  fr = (float)j        * (1.0f / 22.0f); }
        else if (j < 43)  { pos = (float)hh; fr = (float)(j - 22) * (1.0f / 21.0f); }
        else              { pos = (float)ww; fr = (float)(j - 43) * (1.0f / 21.0f); }
        float ang = pos * expf(fr * -9.210340371976184f);
        float c = cosf(ang), sn = sinf(ang);
        e[i][0] = e0 * c - e1 * sn;
        e[i][1] = e0 * sn + e1 * c;
    }
    for (int i = 0; i < 3; ++i) {
        row[cols[i]]     = f2bf(e[i][0]);
        row[cols[i] + 1] = f2bf(e[i][1]);
    }
}

// ---------------- MFMA flash attention v11: 2-wave / 2-q-group ILP ----
// Mechanism target: serial QK->softmax->P->PV chain with only 2 waves/
// SIMD (R3/R5/R9 staging nulls prove not staging-bound; no pipe >52%).
// This version DOUBLES per-wave independent work while CONSERVING
// waves/CU and block count (R1's failure mode was halving waves/CU):
//   2 waves x 2 q-groups = 64 q/block -> 732 blocks (balance 2.86/CU)
//   KVBLK=64 -> LDS 16K(K)+16K(V)+8K(P) = 40KB -> 4 blocks/CU
//   -> 8 waves/CU resident (same as v9/v10), each kf/vf LDS read feeds
//   2 MFMAs, per-tile fixed costs amortize over 2x FLOPs.
// Swizzles: K rows by key&7, V/P rows (128B) by (row&7)<<4 - all
// R3/R8-verified patterns. Single-buffer + __syncthreads (R9 proved
// fancy pipelining buys nothing here).
__global__ __launch_bounds__(128, 2) void attn_mfma(const unsigned short* __restrict__ q,
                                                    const unsigned short* __restrict__ kp,
                                                    const unsigned short* __restrict__ vt,
                                                    unsigned short* __restrict__ o) {
    __shared__ __align__(16) unsigned char Ks[16384];  // 64 keys x 256B (swz key&7)
    __shared__ __align__(16) unsigned char Vs[16384];  // 128 d x 128B keys (swz d&7)
    __shared__ __align__(16) unsigned char Ps[8192];   // 2 waves x 32q x 128B (swz q&7)

    int bid = xcd_swz(blockIdx.x, NHEAD * NKT);
    int h  = bid / NKT;
    int qt = bid % NKT;
    int q0 = qt * 64;
    int tid = threadIdx.x;
    int wave = tid >> 6, lane = tid & 63;   // wave in {0,1}
    int lm = lane & 15, lq = lane >> 4;

    // Q fragments, two q-groups (lane = q-col, regs = d); pre-scaled by qsc
    bf16x8 qf[2][4];
    #pragma unroll
    for (int g = 0; g < 2; ++g) {
        int qr = q0 + wave * 32 + g * 16 + lm; if (qr >= S_TOT) qr = S_TOT - 1;
        const unsigned short* qptr = q + (size_t)qr * C_DIM + h * DHEAD + lq * 8;
        #pragma unroll
        for (int kc = 0; kc < 4; ++kc) qf[g][kc] = *(const bf16x8*)(qptr + kc * 32);
    }

    // K DMA: 16 groups (4 keys x 128 d = 1KB), 8 per wave; key&7 = (g&1)*4+krow
    int krow = lane >> 4;
    int kcolA = ((lane & 15) ^ krow) * 8;
    int kcolB = ((lane & 15) ^ (4 + krow)) * 8;
    // V DMA: 16 groups (8 d-rows x 64 keys = 1KB), 8 per wave; d&7 = lane>>3
    int vr8 = lane >> 3;
    int vslot = (lane & 7) ^ vr8;

    int sxor = (lm & 7) << 4;            // read xor: K key&7 / V d&7 / P q&7 = lm&7
    int ksoff[4], kqoff[4];
    #pragma unroll
    for (int nt = 0; nt < 4; ++nt) ksoff[nt] = (nt * 4 + (lm >> 2)) * 1024 + (lm & 3) * 256;
    #pragma unroll
    for (int kc = 0; kc < 4; ++kc) kqoff[kc] = (kc * 4 + lq) * 16;

    f32x4 oacc[2][8];
    #pragma unroll
    for (int g = 0; g < 2; ++g)
        #pragma unroll
        for (int i = 0; i < 8; ++i) oacc[g][i] = (f32x4){0.f, 0.f, 0.f, 0.f};
    float m_run[2] = {-__builtin_inff(), -__builtin_inff()};   // quad-uniform
    float l_run[2] = {0.f, 0.f};                               // per-lane partials

    for (int kt = 0; kt < NKT; ++kt) {
        int k0 = kt * 64;
        // stage K: 8 groups per wave
        #pragma unroll
        for (int t = 0; t < 8; ++t) {
            int g = wave * 8 + t;
            int grow = k0 + g * 4 + krow; if (grow > S_TOT - 1) grow = S_TOT - 1;
            async16(kp + (size_t)grow * C_DIM + h * DHEAD + ((g & 1) ? kcolB : kcolA),
                    Ks + g * 1024);
        }
        // stage V: 8 groups per wave
        {
            int vcol = k0 + vslot * 8; if (vcol > S_TOT - 8) vcol = S_TOT - 8;
            #pragma unroll
            for (int t = 0; t < 8; ++t) {
                int g = wave * 8 + t;
                async16(vt + (size_t)(h * DHEAD + g * 8 + vr8) * S_TOT + vcol,
                        Vs + g * 1024);
            }
        }
        __syncthreads();               // DMA drained, LDS visible

        // S^T[key][q]: sacc[g][nt] covers keys nt*16.., q-group g
        f32x4 sacc[2][4];
        #pragma unroll
        for (int g = 0; g < 2; ++g)
            #pragma unroll
            for (int nt = 0; nt < 4; ++nt) sacc[g][nt] = (f32x4){0.f, 0.f, 0.f, 0.f};
        #pragma unroll
        for (int kc = 0; kc < 4; ++kc)
            #pragma unroll
            for (int nt = 0; nt < 4; ++nt) {
                bf16x8 kf = *(const bf16x8*)(Ks + ((ksoff[nt] + kqoff[kc]) ^ sxor));
                sacc[0][nt] = __builtin_amdgcn_mfma_f32_16x16x32_bf16(kf, qf[0][kc], sacc[0][nt], 0, 0, 0);
                sacc[1][nt] = __builtin_amdgcn_mfma_f32_16x16x32_bf16(kf, qf[1][kc], sacc[1][nt], 0, 0, 0);
            }
        // mask tail keys
        if (kt == NKT - 1) {
            #pragma unroll
            for (int g = 0; g < 2; ++g)
                #pragma unroll
                for (int nt = 0; nt < 4; ++nt)
                    #pragma unroll
                    for (int r = 0; r < 4; ++r)
                        if (k0 + nt * 16 + lq * 4 + r >= S_TOT) sacc[g][nt][r] = -__builtin_inff();
        }
        // softmax per group: quad-uniform m_run, per-lane partial l (R8 scheme)
        #pragma unroll
        for (int g = 0; g < 2; ++g) {
            float mtr[4];
            #pragma unroll
            for (int nt = 0; nt < 4; ++nt)
                mtr[nt] = fmaxf(fmaxf(sacc[g][nt][0], sacc[g][nt][1]),
                                fmaxf(sacc[g][nt][2], sacc[g][nt][3]));
            float pmax = fmaxf(fmaxf(mtr[0], mtr[1]), fmaxf(mtr[2], mtr[3]));
            int defer = __all(pmax - m_run[g] <= 8.0f);
            if (!defer) {
                float rmax = fmaxf(pmax, __shfl_xor(pmax, 16, 64));
                rmax = fmaxf(rmax, __shfl_xor(rmax, 32, 64));   // quad max
                float mn = fmaxf(m_run[g], rmax);
                float alpha = fexp2(m_run[g] - mn);
                l_run[g] *= alpha;
                #pragma unroll
                for (int i = 0; i < 8; ++i)
                    #pragma unroll
                    for (int r = 0; r < 4; ++r) oacc[g][i][r] *= alpha;
                m_run[g] = mn;
            }
            float rsn[4];
            #pragma unroll
            for (int nt = 0; nt < 4; ++nt) {
                float p0 = fexp2(sacc[g][nt][0] - m_run[g]);
                float p1 = fexp2(sacc[g][nt][1] - m_run[g]);
                float p2 = fexp2(sacc[g][nt][2] - m_run[g]);
                float p3 = fexp2(sacc[g][nt][3] - m_run[g]);
                sacc[g][nt][0] = p0; sacc[g][nt][1] = p1;
                sacc[g][nt][2] = p2; sacc[g][nt][3] = p3;
                rsn[nt] = (p0 + p1) + (p2 + p3);
            }
            l_run[g] += (rsn[0] + rsn[1]) + (rsn[2] + rsn[3]);
            // P^T -> LDS (swz): row = wave*32 + g*16 + lm, 128B rows
            #pragma unroll
            for (int nt = 0; nt < 4; ++nt) {
                uint2 pk;
                pk.x = pk2_trunc(sacc[g][nt][0], sacc[g][nt][1]);
                pk.y = pk2_trunc(sacc[g][nt][2], sacc[g][nt][3]);
                *(uint2*)(Ps + (wave * 4096 + g * 2048 + lm * 128 + ((nt * 32 + lq * 8) ^ sxor))) = pk;
            }
        }
        // PV: O^T[d][q] += V^T[d][key] * P^T[key][q]; each vf feeds 2 MFMAs
        #pragma unroll
        for (int kc = 0; kc < 2; ++kc) {
            bf16x8 pf0 = *(const bf16x8*)(Ps + (wave * 4096 + lm * 128 + ((kc * 64 + lq * 16) ^ sxor)));
            bf16x8 pf1 = *(const bf16x8*)(Ps + (wave * 4096 + 2048 + lm * 128 + ((kc * 64 + lq * 16) ^ sxor)));
            #pragma unroll
            for (int mt = 0; mt < 8; ++mt) {
                bf16x8 vf = *(const bf16x8*)(Vs + ((mt * 16 + lm) * 128 + ((kc * 64 + lq * 16) ^ sxor)));
                oacc[0][mt] = __builtin_amdgcn_mfma_f32_16x16x32_bf16(vf, pf0, oacc[0][mt], 0, 0, 0);
                oacc[1][mt] = __builtin_amdgcn_mfma_f32_16x16x32_bf16(vf, pf1, oacc[1][mt], 0, 0, 0);
            }
        }
        __syncthreads();               // reads done before next stage overwrite
    }
    // epilogue per group: combine per-lane l once, store O
    #pragma unroll
    for (int g = 0; g < 2; ++g) {
        float lt = l_run[g];
        lt += __shfl_xor(lt, 16, 64);
        lt += __shfl_xor(lt, 32, 64);
        int qrow = q0 + wave * 32 + g * 16 + lm;
        if (qrow < S_TOT) {
            float inv = 1.0f / lt;
            #pragma unroll
            for (int mt = 0; mt < 8; ++mt) {
                ushort4 pk;
                pk.x = f2bf(oacc[g][mt][0] * inv);
                pk.y = f2bf(oacc[g][mt][1] * inv);
                pk.z = f2bf(oacc[g][mt][2] * inv);
                pk.w = f2bf(oacc[g][mt][3] * inv);
                *(ushort4*)(o + (size_t)qrow * C_DIM + h * DHEAD + mt * 16 + lq * 4) = pk;
            }
        }
    }
}

// ------ Residual + transpose (S,C) bf16 -> (C,S) out (dual dtype) -----
__global__ __launch_bounds__(256) void resid_t(const unsigned short* __restrict__ proj,
                                               const void* __restrict__ x,
                                               const int* __restrict__ flag,
                                               void* __restrict__ out) {
    int isf32 = *flag;
    __shared__ float tile[32][33];
    int s0 = blockIdx.x * 32, c0 = blockIdx.y * 32;
    int tx = threadIdx.x, ty = threadIdx.y;   // (32,8)
    for (int r = 0; r < 4; ++r) {
        int sl = ty + 8 * r;
        tile[sl][tx] = bf2f(proj[(size_t)(s0 + sl) * C_DIM + (c0 + tx)]);
    }
    __syncthreads();
    for (int r = 0; r < 4; ++r) {
        int cl = ty + 8 * r;
        size_t idx = (size_t)(c0 + cl) * S_TOT + (s0 + tx);
        float val = ldin(x, idx, isf32) + tile[tx][cl];
        if (isf32) ((float*)out)[idx] = val;
        else       ((unsigned short*)out)[idx] = f2bf(val);
    }
}

extern "C" void kernel_launch(void* const* d_in, const int* in_sizes, int n_in,
                              void* d_out, int out_size, void* d_ws, size_t ws_size,
                              hipStream_t stream) {
    const void* x  = d_in[0];
    const void* Wq = d_in[1];
    const void* bq = d_in[2];
    const void* Wk = d_in[3];
    const void* bk = d_in[4];
    const void* Wv = d_in[5];
    const void* bv = d_in[6];
    const void* Wo = d_in[7];
    const void* bo = d_in[8];
    const void* gq = d_in[9];
    const void* gk = d_in[10];

    // ws ~55 MB: xn 11.9 | qb 11.9 | kb 11.9 | Ws0..3 18.9 | small
    char* ws = (char*)d_ws;
    size_t off = 0;
    auto alloc = [&](size_t bytes) -> char* {
        char* p = ws + off;
        off += (bytes + 255) & ~(size_t)255;
        return p;
    };
    const size_t SC = (size_t)S_TOT * C_DIM;
    const size_t WSZ = (size_t)C_DIM * C_DIM * 2;   // 4718592, 256B-aligned
    unsigned short* xn   = (unsigned short*)alloc(SC * 2);
    unsigned short* qb   = (unsigned short*)alloc(SC * 2);
    unsigned short* kb   = (unsigned short*)alloc(SC * 2);
    unsigned short* Ws0  = (unsigned short*)alloc(WSZ);  // Wq (stack head)
    unsigned short* Ws1  = (unsigned short*)alloc(WSZ);  // Wk (contiguous)
    unsigned short* Ws2  = (unsigned short*)alloc(WSZ);  // Wv (contiguous)
    unsigned short* Ws3  = (unsigned short*)alloc(WSZ);  // Wo
    unsigned short* vecs = (unsigned short*)alloc((size_t)6 * C_DIM * 2);
    float* sumb          = (float*)alloc((size_t)S_TOT * 4);
    float* sumsqb        = (float*)alloc((size_t)S_TOT * 4);
    int*   flag          = (int*)alloc(256);
    unsigned short* Vt   = (unsigned short*)d_out;   // [C][S] scratch in d_out
    unsigned short* ob   = xn;   // alias (xn dead after QKV-GEMM)
    unsigned short* proj = qb;   // alias (qb dead after attn)

    (void)Ws1; (void)Ws2;   // accessed via the Ws0 stacked view in gemm2p

    // vecs layout: bq|bk|bv|bo|gq|gk  -> vecs[0..4607] = stacked QKV bias
    unsigned short* bo_b = vecs + 3 * C_DIM;
    unsigned short* gq_b = vecs + 4 * C_DIM;
    unsigned short* gk_b = vecs + 5 * C_DIM;

    const float QSC = 0.12751745f;   // 1/sqrt(128) * log2(e)

    dim3 t328(32, 8);
    dim3 tgrid(S_TOT / 32, C_DIM / 32);             // (121, 48)
    dim3 qkvgrid(31, 24);                           // 744 blocks, N=4608 BN=192
    dim3 ogrid(31, 24);                             // 744 blocks, N=1536 BN=64
    dim3 wgrid((C_DIM * C_DIM) / 2048, 4);          // (1152, 4)
    dim3 sgrid(NKT, 4);                             // (61, 4) ln partials
    dim3 rgrid(S_TOT, 2);

    detect_vecs<<<1, 256, 0, stream>>>((const unsigned short*)x, bq, bk, bv, bo, gq, gk,
                                       flag, vecs, sumb, sumsqb);
    wconv4<<<wgrid, 256, 0, stream>>>(Wq, Wk, Wv, Wo, flag, Ws0, Ws1, Ws2, Ws3);
    ln_stats<<<sgrid, 256, 0, stream>>>(x, flag, sumb, sumsqb);
    ln_norm_t<<<tgrid, t328, 0, stream>>>(x, flag, sumb, sumsqb, xn);

    // fused QKV GEMM: N=4608 (Ws0 = stacked Wq|Wk|Wv), Q->qb, K->kb,
    // V->Vt (transposed [C][S])
    gemm2p<192><<<qkvgrid, 256, 0, stream>>>(xn, Ws0, vecs, qb, kb, Vt, C_DIM, 2 * C_DIM);
    rope2<<<rgrid, 256, 0, stream>>>(qb, kb, gq_b, gk_b, QSC);

    attn_mfma<<<NHEAD * NKT, 128, 0, stream>>>(qb, kb, Vt, ob);

    gemm2p<64><<<ogrid, 256, 0, stream>>>(ob, Ws3, bo_b, proj, proj, proj, 1 << 30, 1 << 30);
    resid_t<<<tgrid, t328, 0, stream>>>(proj, x, flag, d_out);
}